// Round 1
// baseline (325.153 us; speedup 1.0000x reference)
//
#include <hip/hip_runtime.h>
#include <cmath>

#define N_NODES 10000
#define UNITS   64
#define IND     2
#define BATCH   16
#define NEDGE   80000
#define FDIM    66            // IND + UNITS
#define FB      1056          // FDIM*BATCH
#define OG      128           // 2*UNITS
#define OC      64            // UNITS
#define HXS     (N_NODES*UNITS)   // 640000 per batch row
#define INS     (N_NODES*IND)     // 20000 per batch row

// ---------------- reparam: W = mu + exp(logsig)*eps ----------------
__global__ void reparam_kernel(const float* w1mu, const float* w1ls, const float* ew1,
                               const float* b1mu, const float* b1ls, const float* eb1,
                               const float* w2mu, const float* w2ls, const float* ew2,
                               const float* b2mu, const float* b2ls, const float* eb2,
                               float* W1, float* B1, float* W2, float* B2) {
  int i = blockIdx.x * 256 + threadIdx.x;
  if (i < 132 * 128) W1[i] = w1mu[i] + __expf(w1ls[i]) * ew1[i];
  if (i < 132 * 64)  W2[i] = w2mu[i] + __expf(w2ls[i]) * ew2[i];
  if (i < 128)       B1[i] = b1mu[i] + __expf(b1ls[i]) * eb1[i];
  if (i < 64)        B2[i] = b2mu[i] + __expf(b2ls[i]) * eb2[i];
}

// ---------------- build X0: [N][FDIM][BATCH] = concat(inputs, hx) ----------------
__global__ void build_x0_kernel(const float* __restrict__ inputs, const float* __restrict__ hx,
                                float* __restrict__ X0) {
  int i = blockIdx.x * 256 + threadIdx.x;   // i = n*FDIM + f
  if (i >= N_NODES * FDIM) return;
  int n = i / FDIM;
  int f = i - n * FDIM;
  float v[BATCH];
  if (f < IND) {
#pragma unroll
    for (int b = 0; b < BATCH; ++b) v[b] = inputs[(size_t)b * INS + n * IND + f];
  } else {
    int fo = f - IND;
#pragma unroll
    for (int b = 0; b < BATCH; ++b) v[b] = hx[(size_t)b * HXS + n * UNITS + fo];
  }
  float4* dst = reinterpret_cast<float4*>(X0 + (size_t)n * FB + f * BATCH);
  dst[0] = make_float4(v[0], v[1], v[2], v[3]);
  dst[1] = make_float4(v[4], v[5], v[6], v[7]);
  dst[2] = make_float4(v[8], v[9], v[10], v[11]);
  dst[3] = make_float4(v[12], v[13], v[14], v[15]);
}

// ---------------- CSR build ----------------
__global__ void count_kernel(const int* __restrict__ erow, int* __restrict__ cnt) {
  int i = blockIdx.x * 256 + threadIdx.x;
  if (i < NEDGE) atomicAdd(&cnt[erow[i]], 1);
}

__global__ void scan_kernel(const int* __restrict__ cnt, int* __restrict__ rowptr,
                            int* __restrict__ cursor) {
  __shared__ int buf[1024];
  __shared__ int carry_s;
  int t = threadIdx.x;
  if (t == 0) carry_s = 0;
  __syncthreads();
  for (int base = 0; base < N_NODES; base += 1024) {
    int i = base + t;
    int v = (i < N_NODES) ? cnt[i] : 0;
    buf[t] = v;
    __syncthreads();
    for (int off = 1; off < 1024; off <<= 1) {
      int add = (t >= off) ? buf[t - off] : 0;
      __syncthreads();
      buf[t] += add;
      __syncthreads();
    }
    int carry = carry_s;
    int excl = carry + buf[t] - v;
    if (i < N_NODES) { rowptr[i] = excl; cursor[i] = excl; }
    __syncthreads();
    if (t == 1023) carry_s = carry + buf[1023];
    __syncthreads();
  }
  if (t == 0) rowptr[N_NODES] = carry_s;
}

__global__ void fill_kernel(const int* __restrict__ erow, const int* __restrict__ ecol,
                            const float* __restrict__ eval, int* __restrict__ cursor,
                            int* __restrict__ cidx, float* __restrict__ cval) {
  int i = blockIdx.x * 256 + threadIdx.x;
  if (i >= NEDGE) return;
  int r = erow[i];
  int p = atomicAdd(&cursor[r], 1);
  cidx[p] = ecol[i];
  cval[p] = eval[i];
}

// ---------------- gates: gconv1 + sigmoid; writes r*hx into X0c, u into uout ----------------
__global__ __launch_bounds__(256) void gates_kernel(
    const float* __restrict__ X0, const float* __restrict__ W1, const float* __restrict__ B1,
    const int* __restrict__ rowptr, const int* __restrict__ cidx, const float* __restrict__ cval,
    const float* __restrict__ hx, const float* __restrict__ inputs,
    float* __restrict__ X0c, float* __restrict__ uout) {
  __shared__ float xs0[FB];
  __shared__ float xs1[FB];
  int n = blockIdx.x;
  int t = threadIdx.x;
  const float* xrow = X0 + (size_t)n * FB;
  for (int k = t; k < FB; k += 256) xs0[k] = xrow[k];

  // gather x1 = sum_e val * X0[col]
  float g[5] = {0.f, 0.f, 0.f, 0.f, 0.f};
  int e0 = rowptr[n], e1 = rowptr[n + 1];
  for (int e = e0; e < e1; ++e) {
    int c = cidx[e];
    float v = cval[e];
    const float* src = X0 + (size_t)c * FB;
#pragma unroll
    for (int i = 0; i < 4; ++i) g[i] += v * src[t + 256 * i];
    if (t < FB - 1024) g[4] += v * src[t + 1024];
  }
#pragma unroll
  for (int i = 0; i < 4; ++i) xs1[t + 256 * i] = g[i];
  if (t < FB - 1024) xs1[t + 1024] = g[4];
  __syncthreads();

  // GEMM: out[b][o] = sum_f xs0[f][b]*W1[2f][o] + xs1[f][b]*W1[2f+1][o]
  int o = t & 127;
  int bh = t >> 7;  // b in [bh*8, bh*8+8)
  float a[8] = {0.f,0.f,0.f,0.f,0.f,0.f,0.f,0.f};
  for (int f = 0; f < FDIM; ++f) {
    float w0 = W1[(2 * f) * OG + o];
    float w1 = W1[(2 * f + 1) * OG + o];
    const float4* p0 = reinterpret_cast<const float4*>(xs0 + f * BATCH + bh * 8);
    const float4* p1 = reinterpret_cast<const float4*>(xs1 + f * BATCH + bh * 8);
    float4 x00 = p0[0], x01 = p0[1];
    float4 x10 = p1[0], x11 = p1[1];
    a[0] += x00.x * w0 + x10.x * w1;
    a[1] += x00.y * w0 + x10.y * w1;
    a[2] += x00.z * w0 + x10.z * w1;
    a[3] += x00.w * w0 + x10.w * w1;
    a[4] += x01.x * w0 + x11.x * w1;
    a[5] += x01.y * w0 + x11.y * w1;
    a[6] += x01.z * w0 + x11.z * w1;
    a[7] += x01.w * w0 + x11.w * w1;
  }
  float bias = B1[o];
  if (o < UNITS) {
#pragma unroll
    for (int bb = 0; bb < 8; ++bb) {
      int b = bh * 8 + bb;
      float r = 1.f / (1.f + __expf(-(a[bb] + bias)));
      float h = hx[(size_t)b * HXS + n * UNITS + o];
      X0c[(size_t)n * FB + (o + IND) * BATCH + b] = r * h;
    }
  } else {
    int ou = o - UNITS;
#pragma unroll
    for (int bb = 0; bb < 8; ++bb) {
      int b = bh * 8 + bb;
      float u = 1.f / (1.f + __expf(-(a[bb] + bias)));
      uout[(size_t)b * HXS + n * UNITS + ou] = u;
    }
  }
  // copy inputs part (f=0,1) of the row into X0c
  if (t < IND * BATCH) X0c[(size_t)n * FB + t] = xs0[t];
}

// ---------------- candidate: gconv2 + tanh + GRU combine ----------------
__global__ __launch_bounds__(256) void cand_kernel(
    const float* __restrict__ X0c, const float* __restrict__ W2, const float* __restrict__ B2,
    const int* __restrict__ rowptr, const int* __restrict__ cidx, const float* __restrict__ cval,
    const float* __restrict__ hx, float* uo /* u staged in d_out; final out */) {
  __shared__ float xs0[FB];
  __shared__ float xs1[FB];
  int n = blockIdx.x;
  int t = threadIdx.x;
  const float* xrow = X0c + (size_t)n * FB;
  for (int k = t; k < FB; k += 256) xs0[k] = xrow[k];

  float g[5] = {0.f, 0.f, 0.f, 0.f, 0.f};
  int e0 = rowptr[n], e1 = rowptr[n + 1];
  for (int e = e0; e < e1; ++e) {
    int c = cidx[e];
    float v = cval[e];
    const float* src = X0c + (size_t)c * FB;
#pragma unroll
    for (int i = 0; i < 4; ++i) g[i] += v * src[t + 256 * i];
    if (t < FB - 1024) g[4] += v * src[t + 1024];
  }
#pragma unroll
  for (int i = 0; i < 4; ++i) xs1[t + 256 * i] = g[i];
  if (t < FB - 1024) xs1[t + 1024] = g[4];
  __syncthreads();

  // GEMM: out[b][o] over o in [0,64); thread: o = t&63, bq = t>>6 -> 4 b's
  int o = t & 63;
  int bq = t >> 6;
  float a[4] = {0.f, 0.f, 0.f, 0.f};
  for (int f = 0; f < FDIM; ++f) {
    float w0 = W2[(2 * f) * OC + o];
    float w1 = W2[(2 * f + 1) * OC + o];
    const float4 x0v = *reinterpret_cast<const float4*>(xs0 + f * BATCH + bq * 4);
    const float4 x1v = *reinterpret_cast<const float4*>(xs1 + f * BATCH + bq * 4);
    a[0] += x0v.x * w0 + x1v.x * w1;
    a[1] += x0v.y * w0 + x1v.y * w1;
    a[2] += x0v.z * w0 + x1v.z * w1;
    a[3] += x0v.w * w0 + x1v.w * w1;
  }
  float bias = B2[o];
#pragma unroll
  for (int bb = 0; bb < 4; ++bb) {
    int b = bq * 4 + bb;
    float c = tanhf(a[bb] + bias);
    size_t idx = (size_t)b * HXS + n * UNITS + o;
    float u = uo[idx];
    float h = hx[idx];
    uo[idx] = u * h + (1.f - u) * c;
  }
}

extern "C" void kernel_launch(void* const* d_in, const int* in_sizes, int n_in,
                              void* d_out, int out_size, void* d_ws, size_t ws_size,
                              hipStream_t stream) {
  const float* inputs = (const float*)d_in[0];
  const float* hx     = (const float*)d_in[1];
  const float* eval   = (const float*)d_in[2];
  const float* w1mu   = (const float*)d_in[3];
  const float* w1ls   = (const float*)d_in[4];
  const float* b1mu   = (const float*)d_in[5];
  const float* b1ls   = (const float*)d_in[6];
  const float* w2mu   = (const float*)d_in[7];
  const float* w2ls   = (const float*)d_in[8];
  const float* b2mu   = (const float*)d_in[9];
  const float* b2ls   = (const float*)d_in[10];
  const float* ew1    = (const float*)d_in[11];
  const float* eb1    = (const float*)d_in[12];
  const float* ew2    = (const float*)d_in[13];
  const float* eb2    = (const float*)d_in[14];
  const int* erow     = (const int*)d_in[15];
  const int* ecol     = (const int*)d_in[16];
  float* out = (float*)d_out;

  float* ws  = (float*)d_ws;
  float* W1  = ws;                         // 16896
  float* B1  = W1 + 16896;                 // 128
  float* W2  = B1 + 128;                   // 8448
  float* B2  = W2 + 8448;                  // 64
  float* X0  = B2 + 64;                    // N*FB
  float* X0c = X0 + (size_t)N_NODES * FB;  // N*FB
  int* cnt    = (int*)(X0c + (size_t)N_NODES * FB);
  int* rowptr = cnt + 10016;
  int* cursor = rowptr + 10016;
  int* cidx   = cursor + 10016;
  float* cval = (float*)(cidx + NEDGE);

  reparam_kernel<<<66, 256, 0, stream>>>(w1mu, w1ls, ew1, b1mu, b1ls, eb1,
                                         w2mu, w2ls, ew2, b2mu, b2ls, eb2,
                                         W1, B1, W2, B2);
  build_x0_kernel<<<(N_NODES * FDIM + 255) / 256, 256, 0, stream>>>(inputs, hx, X0);
  hipMemsetAsync(cnt, 0, 10016 * sizeof(int), stream);
  count_kernel<<<(NEDGE + 255) / 256, 256, 0, stream>>>(erow, cnt);
  scan_kernel<<<1, 1024, 0, stream>>>(cnt, rowptr, cursor);
  fill_kernel<<<(NEDGE + 255) / 256, 256, 0, stream>>>(erow, ecol, eval, cursor, cidx, cval);
  gates_kernel<<<N_NODES, 256, 0, stream>>>(X0, W1, B1, rowptr, cidx, cval, hx, inputs, X0c, out);
  cand_kernel<<<N_NODES, 256, 0, stream>>>(X0c, W2, B2, rowptr, cidx, cval, hx, out);
}

// Round 2
// 220.296 us; speedup vs baseline: 1.4760x; 1.4760x over previous
//
#include <hip/hip_runtime.h>
#include <cmath>

#define N_NODES 10000
#define UNITS   64
#define IND     2
#define BATCH   16
#define NEDGE   80000
#define FDIM    66            // IND + UNITS
#define FB      1056          // FDIM*BATCH
#define OG      128           // 2*UNITS
#define OC      64            // UNITS
#define HXS     (N_NODES*UNITS)
#define INS     (N_NODES*IND)
#define KTILES  5             // ceil(132/32)

typedef __attribute__((ext_vector_type(8))) short bf16x8;
typedef __attribute__((ext_vector_type(4))) float f32x4;

__device__ __forceinline__ short f2bf(float x) {
  union { float f; unsigned u; } v; v.f = x;
  unsigned r = v.u + 0x7fffu + ((v.u >> 16) & 1u);
  return (short)(r >> 16);
}

// ---------------- reparam: W = mu + exp(logsig)*eps (fp32) ----------------
__global__ void reparam_kernel(const float* w1mu, const float* w1ls, const float* ew1,
                               const float* b1mu, const float* b1ls, const float* eb1,
                               const float* w2mu, const float* w2ls, const float* ew2,
                               const float* b2mu, const float* b2ls, const float* eb2,
                               float* W1, float* B1, float* W2, float* B2) {
  int i = blockIdx.x * 256 + threadIdx.x;
  if (i < 132 * 128) W1[i] = w1mu[i] + __expf(w1ls[i]) * ew1[i];
  if (i < 132 * 64)  W2[i] = w2mu[i] + __expf(w2ls[i]) * ew2[i];
  if (i < 128)       B1[i] = b1mu[i] + __expf(b1ls[i]) * eb1[i];
  if (i < 64)        B2[i] = b2mu[i] + __expf(b2ls[i]) * eb2[i];
}

// ---------------- pack W into MFMA B-fragment lane order (bf16) ----------------
// B-frag layout for mfma_f32_16x16x32_bf16: lane l holds B[k][n] with
// n = nt*16 + (l&15), k = kt*32 + (l>>4)*8 + j  (j = 0..7)
__global__ void pack_kernel(const float* __restrict__ W1, const float* __restrict__ W2,
                            short* __restrict__ W1p, short* __restrict__ W2p) {
  int i = blockIdx.x * 256 + threadIdx.x;   // 8*5*64 = 2560 for W1, 4*5*64 = 1280 for W2
  if (i < 2560) {
    int l = i & 63, kt = (i >> 6) % KTILES, nt = i / (KTILES * 64);
    int o = nt * 16 + (l & 15);
    bf16x8 fr;
#pragma unroll
    for (int j = 0; j < 8; ++j) {
      int k = kt * 32 + (l >> 4) * 8 + j;
      fr[j] = (k < 2 * FDIM) ? f2bf(W1[k * OG + o]) : (short)0;
    }
    *((bf16x8*)W1p + i) = fr;
  } else if (i < 3840) {
    int i2 = i - 2560;
    int l = i2 & 63, kt = (i2 >> 6) % KTILES, nt = i2 / (KTILES * 64);
    int o = nt * 16 + (l & 15);
    bf16x8 fr;
#pragma unroll
    for (int j = 0; j < 8; ++j) {
      int k = kt * 32 + (l >> 4) * 8 + j;
      fr[j] = (k < 2 * FDIM) ? f2bf(W2[k * OC + o]) : (short)0;
    }
    *((bf16x8*)W2p + i2) = fr;
  }
}

// ---------------- build X0: [N][FDIM][BATCH] = concat(inputs, hx) ----------------
__global__ void build_x0_kernel(const float* __restrict__ inputs, const float* __restrict__ hx,
                                float* __restrict__ X0) {
  int i = blockIdx.x * 256 + threadIdx.x;   // i = n*FDIM + f
  if (i >= N_NODES * FDIM) return;
  int n = i / FDIM;
  int f = i - n * FDIM;
  float v[BATCH];
  if (f < IND) {
#pragma unroll
    for (int b = 0; b < BATCH; ++b) v[b] = inputs[(size_t)b * INS + n * IND + f];
  } else {
    int fo = f - IND;
#pragma unroll
    for (int b = 0; b < BATCH; ++b) v[b] = hx[(size_t)b * HXS + n * UNITS + fo];
  }
  float4* dst = reinterpret_cast<float4*>(X0 + (size_t)n * FB + f * BATCH);
  dst[0] = make_float4(v[0], v[1], v[2], v[3]);
  dst[1] = make_float4(v[4], v[5], v[6], v[7]);
  dst[2] = make_float4(v[8], v[9], v[10], v[11]);
  dst[3] = make_float4(v[12], v[13], v[14], v[15]);
}

// ---------------- CSR build ----------------
__global__ void count_kernel(const int* __restrict__ erow, int* __restrict__ cnt) {
  int i = blockIdx.x * 256 + threadIdx.x;
  if (i < NEDGE) atomicAdd(&cnt[erow[i]], 1);
}

__global__ void scan_kernel(const int* __restrict__ cnt, int* __restrict__ rowptr,
                            int* __restrict__ cursor) {
  __shared__ int buf[1024];
  __shared__ int carry_s;
  int t = threadIdx.x;
  if (t == 0) carry_s = 0;
  __syncthreads();
  for (int base = 0; base < N_NODES; base += 1024) {
    int i = base + t;
    int v = (i < N_NODES) ? cnt[i] : 0;
    buf[t] = v;
    __syncthreads();
    for (int off = 1; off < 1024; off <<= 1) {
      int add = (t >= off) ? buf[t - off] : 0;
      __syncthreads();
      buf[t] += add;
      __syncthreads();
    }
    int carry = carry_s;
    int excl = carry + buf[t] - v;
    if (i < N_NODES) { rowptr[i] = excl; cursor[i] = excl; }
    __syncthreads();
    if (t == 1023) carry_s = carry + buf[1023];
    __syncthreads();
  }
  if (t == 0) rowptr[N_NODES] = carry_s;
}

__global__ void fill_kernel(const int* __restrict__ erow, const int* __restrict__ ecol,
                            const float* __restrict__ eval, int* __restrict__ cursor,
                            int* __restrict__ cidx, float* __restrict__ cval) {
  int i = blockIdx.x * 256 + threadIdx.x;
  if (i >= NEDGE) return;
  int r = erow[i];
  int p = atomicAdd(&cursor[r], 1);
  cidx[p] = ecol[i];
  cval[p] = eval[i];
}

// ---------------- gates: gconv1 (MFMA) + sigmoid; writes r*hx into X0c, u into uout ----------------
__global__ __launch_bounds__(256) void gates_kernel(
    const float* __restrict__ X0, const short* __restrict__ W1p, const float* __restrict__ B1,
    const int* __restrict__ rowptr, const int* __restrict__ cidx, const float* __restrict__ cval,
    const float* __restrict__ hx,
    float* __restrict__ X0c, float* __restrict__ uout) {
  __shared__ float xs0[FB];   // [f][b]
  __shared__ float xs1[FB];
  int n = blockIdx.x;
  int t = threadIdx.x;
  const float* xrow = X0 + (size_t)n * FB;
  for (int k = t; k < FB; k += 256) xs0[k] = xrow[k];

  // gather x1 = sum_e val * X0[col]
  float g[5] = {0.f, 0.f, 0.f, 0.f, 0.f};
  int e0 = rowptr[n], e1 = rowptr[n + 1];
  for (int e = e0; e < e1; ++e) {
    int c = cidx[e];
    float v = cval[e];
    const float* src = X0 + (size_t)c * FB;
#pragma unroll
    for (int i = 0; i < 4; ++i) g[i] += v * src[t + 256 * i];
    if (t < FB - 1024) g[4] += v * src[t + 1024];
  }
#pragma unroll
  for (int i = 0; i < 4; ++i) xs1[t + 256 * i] = g[i];
  if (t < FB - 1024) xs1[t + 1024] = g[4];
  __syncthreads();

  int lane = t & 63, w = t >> 6;
  int ml = lane & 15, s = lane >> 4;
  // A-frag: lane holds A[m][k], m = lane&15 (batch), k = kt*32 + (lane>>4)*8 + j
  // feature index k -> f = k>>1, source = (k&1) ? x1 : x0
  bf16x8 af[KTILES];
#pragma unroll
  for (int kt = 0; kt < KTILES; ++kt) {
#pragma unroll
    for (int j = 0; j < 8; ++j) {
      int k = kt * 32 + s * 8 + j;
      float v = 0.f;
      if (k < 2 * FDIM) v = (k & 1) ? xs1[(k >> 1) * BATCH + ml] : xs0[(k >> 1) * BATCH + ml];
      af[kt][j] = f2bf(v);
    }
  }
  const bf16x8* Wp = (const bf16x8*)W1p;
#pragma unroll
  for (int q = 0; q < 2; ++q) {
    int nt = w * 2 + q;
    f32x4 acc = {0.f, 0.f, 0.f, 0.f};
#pragma unroll
    for (int kt = 0; kt < KTILES; ++kt)
      acc = __builtin_amdgcn_mfma_f32_16x16x32_bf16(af[kt], Wp[(nt * KTILES + kt) * 64 + lane],
                                                    acc, 0, 0, 0);
    // D: n-col = lane&15 -> output o = nt*16+ml ; m-row = s*4+r -> batch
    int o = nt * 16 + ml;
    float bias = B1[o];
    if (o < UNITS) {
      float4 rv;
      float* rvp = &rv.x;
#pragma unroll
      for (int r = 0; r < 4; ++r) {
        int b = s * 4 + r;
        float sg = 1.f / (1.f + __expf(-(acc[r] + bias)));
        rvp[r] = sg * hx[(size_t)b * HXS + n * UNITS + o];
      }
      *reinterpret_cast<float4*>(X0c + (size_t)n * FB + (o + IND) * BATCH + s * 4) = rv;
    } else {
      int ou = o - UNITS;
#pragma unroll
      for (int r = 0; r < 4; ++r) {
        int b = s * 4 + r;
        float sg = 1.f / (1.f + __expf(-(acc[r] + bias)));
        uout[(size_t)b * HXS + n * UNITS + ou] = sg;
      }
    }
  }
  // copy inputs part (f=0,1) of the row into X0c
  if (t < IND * BATCH) X0c[(size_t)n * FB + t] = xs0[t];
}

// ---------------- candidate: gconv2 (MFMA) + tanh + GRU combine ----------------
__global__ __launch_bounds__(256) void cand_kernel(
    const float* __restrict__ X0c, const short* __restrict__ W2p, const float* __restrict__ B2,
    const int* __restrict__ rowptr, const int* __restrict__ cidx, const float* __restrict__ cval,
    const float* __restrict__ hx, float* uo /* u staged in d_out; final out */) {
  __shared__ float xs0[FB];
  __shared__ float xs1[FB];
  int n = blockIdx.x;
  int t = threadIdx.x;
  const float* xrow = X0c + (size_t)n * FB;
  for (int k = t; k < FB; k += 256) xs0[k] = xrow[k];

  float g[5] = {0.f, 0.f, 0.f, 0.f, 0.f};
  int e0 = rowptr[n], e1 = rowptr[n + 1];
  for (int e = e0; e < e1; ++e) {
    int c = cidx[e];
    float v = cval[e];
    const float* src = X0c + (size_t)c * FB;
#pragma unroll
    for (int i = 0; i < 4; ++i) g[i] += v * src[t + 256 * i];
    if (t < FB - 1024) g[4] += v * src[t + 1024];
  }
#pragma unroll
  for (int i = 0; i < 4; ++i) xs1[t + 256 * i] = g[i];
  if (t < FB - 1024) xs1[t + 1024] = g[4];
  __syncthreads();

  int lane = t & 63, w = t >> 6;
  int ml = lane & 15, s = lane >> 4;
  bf16x8 af[KTILES];
#pragma unroll
  for (int kt = 0; kt < KTILES; ++kt) {
#pragma unroll
    for (int j = 0; j < 8; ++j) {
      int k = kt * 32 + s * 8 + j;
      float v = 0.f;
      if (k < 2 * FDIM) v = (k & 1) ? xs1[(k >> 1) * BATCH + ml] : xs0[(k >> 1) * BATCH + ml];
      af[kt][j] = f2bf(v);
    }
  }
  const bf16x8* Wp = (const bf16x8*)W2p;
  int nt = w;
  f32x4 acc = {0.f, 0.f, 0.f, 0.f};
#pragma unroll
  for (int kt = 0; kt < KTILES; ++kt)
    acc = __builtin_amdgcn_mfma_f32_16x16x32_bf16(af[kt], Wp[(nt * KTILES + kt) * 64 + lane],
                                                  acc, 0, 0, 0);
  int o = nt * 16 + ml;
  float bias = B2[o];
#pragma unroll
  for (int r = 0; r < 4; ++r) {
    int b = s * 4 + r;
    size_t idx = (size_t)b * HXS + n * UNITS + o;
    // fast tanh via exp2-free form: tanh(x) = 1 - 2/(e^{2x}+1)
    float x = acc[r] + bias;
    float c = 1.f - 2.f / (__expf(2.f * x) + 1.f);
    float u = uo[idx];
    float h = hx[idx];
    uo[idx] = u * h + (1.f - u) * c;
  }
}

extern "C" void kernel_launch(void* const* d_in, const int* in_sizes, int n_in,
                              void* d_out, int out_size, void* d_ws, size_t ws_size,
                              hipStream_t stream) {
  const float* inputs = (const float*)d_in[0];
  const float* hx     = (const float*)d_in[1];
  const float* eval   = (const float*)d_in[2];
  const float* w1mu   = (const float*)d_in[3];
  const float* w1ls   = (const float*)d_in[4];
  const float* b1mu   = (const float*)d_in[5];
  const float* b1ls   = (const float*)d_in[6];
  const float* w2mu   = (const float*)d_in[7];
  const float* w2ls   = (const float*)d_in[8];
  const float* b2mu   = (const float*)d_in[9];
  const float* b2ls   = (const float*)d_in[10];
  const float* ew1    = (const float*)d_in[11];
  const float* eb1    = (const float*)d_in[12];
  const float* ew2    = (const float*)d_in[13];
  const float* eb2    = (const float*)d_in[14];
  const int* erow     = (const int*)d_in[15];
  const int* ecol     = (const int*)d_in[16];
  float* out = (float*)d_out;

  float* ws  = (float*)d_ws;
  float* W1  = ws;                         // 16896
  float* B1  = W1 + 16896;                 // 128
  float* W2  = B1 + 128;                   // 8448
  float* B2  = W2 + 8448;                  // 64
  float* X0  = B2 + 64;                    // N*FB
  float* X0c = X0 + (size_t)N_NODES * FB;  // N*FB
  int* cnt    = (int*)(X0c + (size_t)N_NODES * FB);
  int* rowptr = cnt + 10016;
  int* cursor = rowptr + 10016;
  int* cidx   = cursor + 10016;
  float* cval = (float*)(cidx + NEDGE);
  short* W1p  = (short*)(cval + NEDGE);    // 8*5*64*8 = 20480 shorts (16B aligned)
  short* W2p  = W1p + 20480;               // 4*5*64*8 = 10240 shorts

  reparam_kernel<<<66, 256, 0, stream>>>(w1mu, w1ls, ew1, b1mu, b1ls, eb1,
                                         w2mu, w2ls, ew2, b2mu, b2ls, eb2,
                                         W1, B1, W2, B2);
  pack_kernel<<<15, 256, 0, stream>>>(W1, W2, W1p, W2p);
  build_x0_kernel<<<(N_NODES * FDIM + 255) / 256, 256, 0, stream>>>(inputs, hx, X0);
  hipMemsetAsync(cnt, 0, 10016 * sizeof(int), stream);
  count_kernel<<<(NEDGE + 255) / 256, 256, 0, stream>>>(erow, cnt);
  scan_kernel<<<1, 1024, 0, stream>>>(cnt, rowptr, cursor);
  fill_kernel<<<(NEDGE + 255) / 256, 256, 0, stream>>>(erow, ecol, eval, cursor, cidx, cval);
  gates_kernel<<<N_NODES, 256, 0, stream>>>(X0, W1p, B1, rowptr, cidx, cval, hx, X0c, out);
  cand_kernel<<<N_NODES, 256, 0, stream>>>(X0c, W2p, B2, rowptr, cidx, cval, hx, out);
}

// Round 3
// 150.138 us; speedup vs baseline: 2.1657x; 1.4673x over previous
//
#include <hip/hip_runtime.h>
#include <cmath>

#define N_NODES 10000
#define UNITS   64
#define IND     2
#define BATCH   16
#define NEDGE   80000
#define FDIM    66            // IND + UNITS
#define FB      1056          // FDIM*BATCH (elements per node row)
#define OG      128           // 2*UNITS
#define OC      64            // UNITS
#define HXS     (N_NODES*UNITS)
#define INS     (N_NODES*IND)
#define KTILES  5             // ceil(132/32)
#define NCHUNK  264           // FB/4 u16x4 chunks per row

typedef __attribute__((ext_vector_type(8))) short bf16x8;
typedef __attribute__((ext_vector_type(4))) float f32x4;
typedef __attribute__((ext_vector_type(4))) unsigned short u16x4;
typedef __attribute__((ext_vector_type(8))) unsigned short u16x8;

__device__ __forceinline__ unsigned short f2bf(float x) {
  union { float f; unsigned u; } v; v.f = x;
  unsigned r = v.u + 0x7fffu + ((v.u >> 16) & 1u);
  return (unsigned short)(r >> 16);
}
__device__ __forceinline__ float bf2f(unsigned short u) {
  union { unsigned u; float f; } v; v.u = ((unsigned)u) << 16; return v.f;
}

// ------- pack W (with fused reparam) into MFMA B-frag lane order + biases -------
// B-frag for mfma_f32_16x16x32_bf16: lane l holds B[k][n], n = nt*16+(l&15),
// k = kt*32 + (l>>4)*8 + j
__global__ void pack_kernel(const float* __restrict__ w1mu, const float* __restrict__ w1ls,
                            const float* __restrict__ ew1,
                            const float* __restrict__ b1mu, const float* __restrict__ b1ls,
                            const float* __restrict__ eb1,
                            const float* __restrict__ w2mu, const float* __restrict__ w2ls,
                            const float* __restrict__ ew2,
                            const float* __restrict__ b2mu, const float* __restrict__ b2ls,
                            const float* __restrict__ eb2,
                            short* __restrict__ W1p, short* __restrict__ W2p,
                            float* __restrict__ B1, float* __restrict__ B2) {
  int i = blockIdx.x * 256 + threadIdx.x;
  if (i < 2560) {
    int l = i & 63, kt = (i >> 6) % KTILES, nt = i / (KTILES * 64);
    int o = nt * 16 + (l & 15);
    bf16x8 fr;
#pragma unroll
    for (int j = 0; j < 8; ++j) {
      int k = kt * 32 + (l >> 4) * 8 + j;
      float w = 0.f;
      if (k < 2 * FDIM) { int idx = k * OG + o; w = w1mu[idx] + __expf(w1ls[idx]) * ew1[idx]; }
      fr[j] = (short)f2bf(w);
    }
    *((bf16x8*)W1p + i) = fr;
  } else if (i < 3840) {
    int i2 = i - 2560;
    int l = i2 & 63, kt = (i2 >> 6) % KTILES, nt = i2 / (KTILES * 64);
    int o = nt * 16 + (l & 15);
    bf16x8 fr;
#pragma unroll
    for (int j = 0; j < 8; ++j) {
      int k = kt * 32 + (l >> 4) * 8 + j;
      float w = 0.f;
      if (k < 2 * FDIM) { int idx = k * OC + o; w = w2mu[idx] + __expf(w2ls[idx]) * ew2[idx]; }
      fr[j] = (short)f2bf(w);
    }
    *((bf16x8*)W2p + i2) = fr;
  } else if (i < 3968) {
    int j = i - 3840; B1[j] = b1mu[j] + __expf(b1ls[j]) * eb1[j];
  } else if (i < 4032) {
    int j = i - 3968; B2[j] = b2mu[j] + __expf(b2ls[j]) * eb2[j];
  }
}

// ------- build X0 (bf16 [N][66][16]) + zero cnt -------
__global__ void build_x0_kernel(const float* __restrict__ inputs, const float* __restrict__ hx,
                                unsigned short* __restrict__ X0, int* __restrict__ cnt) {
  int i = blockIdx.x * 256 + threadIdx.x;   // i = n*FDIM + f
  if (i < 10016) cnt[i] = 0;
  if (i >= N_NODES * FDIM) return;
  int n = i / FDIM;
  int f = i - n * FDIM;
  unsigned short v[BATCH];
  if (f < IND) {
#pragma unroll
    for (int b = 0; b < BATCH; ++b) v[b] = f2bf(inputs[(size_t)b * INS + n * IND + f]);
  } else {
    int fo = f - IND;
#pragma unroll
    for (int b = 0; b < BATCH; ++b) v[b] = f2bf(hx[(size_t)b * HXS + n * UNITS + fo]);
  }
  u16x8* dst = reinterpret_cast<u16x8*>(X0 + (size_t)n * FB + f * BATCH);
  u16x8 lo, hi;
#pragma unroll
  for (int b = 0; b < 8; ++b) { lo[b] = v[b]; hi[b] = v[b + 8]; }
  dst[0] = lo; dst[1] = hi;
}

// ------- CSR build -------
__global__ void count_kernel(const int* __restrict__ erow, int* __restrict__ cnt) {
  int i = blockIdx.x * 256 + threadIdx.x;
  if (i < NEDGE) atomicAdd(&cnt[erow[i]], 1);
}

__global__ void scan_kernel(const int* __restrict__ cnt, int* __restrict__ rowptr,
                            int* __restrict__ cursor) {
  __shared__ int buf[1024];
  __shared__ int carry_s;
  int t = threadIdx.x;
  if (t == 0) carry_s = 0;
  __syncthreads();
  for (int base = 0; base < N_NODES; base += 1024) {
    int i = base + t;
    int v = (i < N_NODES) ? cnt[i] : 0;
    buf[t] = v;
    __syncthreads();
    for (int off = 1; off < 1024; off <<= 1) {
      int add = (t >= off) ? buf[t - off] : 0;
      __syncthreads();
      buf[t] += add;
      __syncthreads();
    }
    int carry = carry_s;
    int excl = carry + buf[t] - v;
    if (i < N_NODES) { rowptr[i] = excl; cursor[i] = excl; }
    __syncthreads();
    if (t == 1023) carry_s = carry + buf[1023];
    __syncthreads();
  }
  if (t == 0) rowptr[N_NODES] = carry_s;
}

__global__ void fill_kernel(const int* __restrict__ erow, const int* __restrict__ ecol,
                            const float* __restrict__ eval, int* __restrict__ cursor,
                            int* __restrict__ cidx, float* __restrict__ cval) {
  int i = blockIdx.x * 256 + threadIdx.x;
  if (i >= NEDGE) return;
  int r = erow[i];
  int p = atomicAdd(&cursor[r], 1);
  cidx[p] = ecol[i];
  cval[p] = eval[i];
}

// ------- shared gather: stage row -> xs0, CSR gather -> xs1 (both bf16) -------
__device__ __forceinline__ void gather_node(const unsigned short* __restrict__ X,
                                            const int* __restrict__ rowptr,
                                            const int* __restrict__ cidx,
                                            const float* __restrict__ cval,
                                            int n, int t,
                                            unsigned short* xs0, unsigned short* xs1) {
  const bool extra = t < (NCHUNK - 256);
  const u16x4* xrow = reinterpret_cast<const u16x4*>(X + (size_t)n * FB);
  reinterpret_cast<u16x4*>(xs0)[t] = xrow[t];
  if (extra) reinterpret_cast<u16x4*>(xs0)[256 + t] = xrow[256 + t];

  float g[4] = {0.f, 0.f, 0.f, 0.f};
  float ge[4] = {0.f, 0.f, 0.f, 0.f};
  int e = rowptr[n], e1 = rowptr[n + 1];
  for (; e + 2 <= e1; e += 2) {
    int ca = cidx[e], cb = cidx[e + 1];
    float va = cval[e], vb = cval[e + 1];
    const u16x4* sa = reinterpret_cast<const u16x4*>(X + (size_t)ca * FB);
    const u16x4* sb = reinterpret_cast<const u16x4*>(X + (size_t)cb * FB);
    u16x4 Aa = sa[t], Ab = sb[t];
    if (extra) {
      u16x4 Ea = sa[256 + t], Eb = sb[256 + t];
#pragma unroll
      for (int j = 0; j < 4; ++j) ge[j] += va * bf2f(Ea[j]) + vb * bf2f(Eb[j]);
    }
#pragma unroll
    for (int j = 0; j < 4; ++j) g[j] += va * bf2f(Aa[j]) + vb * bf2f(Ab[j]);
  }
  if (e < e1) {
    int ca = cidx[e];
    float va = cval[e];
    const u16x4* sa = reinterpret_cast<const u16x4*>(X + (size_t)ca * FB);
    u16x4 Aa = sa[t];
    if (extra) {
      u16x4 Ea = sa[256 + t];
#pragma unroll
      for (int j = 0; j < 4; ++j) ge[j] += va * bf2f(Ea[j]);
    }
#pragma unroll
    for (int j = 0; j < 4; ++j) g[j] += va * bf2f(Aa[j]);
  }
  u16x4 w0;
#pragma unroll
  for (int j = 0; j < 4; ++j) w0[j] = f2bf(g[j]);
  reinterpret_cast<u16x4*>(xs1)[t] = w0;
  if (extra) {
    u16x4 w1;
#pragma unroll
    for (int j = 0; j < 4; ++j) w1[j] = f2bf(ge[j]);
    reinterpret_cast<u16x4*>(xs1)[256 + t] = w1;
  }
  __syncthreads();
}

// A-frag: lane holds A[m][k], m = lane&15 (batch), k = kt*32 + (lane>>4)*8 + j
__device__ __forceinline__ void build_afrag(const unsigned short* xs0,
                                            const unsigned short* xs1,
                                            int ml, int s, bf16x8* af) {
#pragma unroll
  for (int kt = 0; kt < KTILES; ++kt) {
#pragma unroll
    for (int j = 0; j < 8; ++j) {
      int k = kt * 32 + s * 8 + j;
      unsigned short u = 0;
      if (k < 2 * FDIM) u = (k & 1) ? xs1[(k >> 1) * BATCH + ml] : xs0[(k >> 1) * BATCH + ml];
      af[kt][j] = (short)u;
    }
  }
}

// ------- gates: gconv1 (MFMA) + sigmoid; r*hx -> X0c (bf16), u -> uout -------
__global__ __launch_bounds__(256) void gates_kernel(
    const unsigned short* __restrict__ X0, const short* __restrict__ W1p,
    const float* __restrict__ B1,
    const int* __restrict__ rowptr, const int* __restrict__ cidx, const float* __restrict__ cval,
    const float* __restrict__ hx,
    unsigned short* __restrict__ X0c, float* __restrict__ uout) {
  __shared__ __align__(16) unsigned short xs0[FB];
  __shared__ __align__(16) unsigned short xs1[FB];
  int n = blockIdx.x;
  int t = threadIdx.x;
  gather_node(X0, rowptr, cidx, cval, n, t, xs0, xs1);

  int lane = t & 63, w = t >> 6;
  int ml = lane & 15, s = lane >> 4;
  bf16x8 af[KTILES];
  build_afrag(xs0, xs1, ml, s, af);

  const bf16x8* Wp = (const bf16x8*)W1p;
#pragma unroll
  for (int q = 0; q < 2; ++q) {
    int nt = w * 2 + q;
    f32x4 acc = {0.f, 0.f, 0.f, 0.f};
#pragma unroll
    for (int kt = 0; kt < KTILES; ++kt)
      acc = __builtin_amdgcn_mfma_f32_16x16x32_bf16(af[kt], Wp[(nt * KTILES + kt) * 64 + lane],
                                                    acc, 0, 0, 0);
    int o = nt * 16 + ml;        // output col; rows = batch s*4+r
    float bias = B1[o];
    if (o < UNITS) {
      u16x4 rv;
#pragma unroll
      for (int r = 0; r < 4; ++r) {
        int b = s * 4 + r;
        float sg = 1.f / (1.f + __expf(-(acc[r] + bias)));
        rv[r] = f2bf(sg * hx[(size_t)b * HXS + n * UNITS + o]);
      }
      *reinterpret_cast<u16x4*>(X0c + (size_t)n * FB + (o + IND) * BATCH + s * 4) = rv;
    } else {
      int ou = o - UNITS;
#pragma unroll
      for (int r = 0; r < 4; ++r) {
        int b = s * 4 + r;
        float sg = 1.f / (1.f + __expf(-(acc[r] + bias)));
        uout[(size_t)b * HXS + n * UNITS + ou] = sg;
      }
    }
  }
  // inputs part (f=0,1) of the row into X0c
  if (t < IND * BATCH) X0c[(size_t)n * FB + t] = xs0[t];
}

// ------- candidate: gconv2 (MFMA) + tanh + GRU combine -------
__global__ __launch_bounds__(256) void cand_kernel(
    const unsigned short* __restrict__ X0c, const short* __restrict__ W2p,
    const float* __restrict__ B2,
    const int* __restrict__ rowptr, const int* __restrict__ cidx, const float* __restrict__ cval,
    const float* __restrict__ hx, float* uo /* u staged in d_out; final out */) {
  __shared__ __align__(16) unsigned short xs0[FB];
  __shared__ __align__(16) unsigned short xs1[FB];
  int n = blockIdx.x;
  int t = threadIdx.x;
  gather_node(X0c, rowptr, cidx, cval, n, t, xs0, xs1);

  int lane = t & 63, w = t >> 6;
  int ml = lane & 15, s = lane >> 4;
  bf16x8 af[KTILES];
  build_afrag(xs0, xs1, ml, s, af);

  const bf16x8* Wp = (const bf16x8*)W2p;
  int nt = w;
  f32x4 acc = {0.f, 0.f, 0.f, 0.f};
#pragma unroll
  for (int kt = 0; kt < KTILES; ++kt)
    acc = __builtin_amdgcn_mfma_f32_16x16x32_bf16(af[kt], Wp[(nt * KTILES + kt) * 64 + lane],
                                                  acc, 0, 0, 0);
  int o = nt * 16 + ml;
  float bias = B2[o];
#pragma unroll
  for (int r = 0; r < 4; ++r) {
    int b = s * 4 + r;
    size_t idx = (size_t)b * HXS + n * UNITS + o;
    float x = acc[r] + bias;
    float c = 1.f - 2.f / (__expf(2.f * x) + 1.f);   // tanh
    float u = uo[idx];
    float h = hx[idx];
    uo[idx] = u * h + (1.f - u) * c;
  }
}

extern "C" void kernel_launch(void* const* d_in, const int* in_sizes, int n_in,
                              void* d_out, int out_size, void* d_ws, size_t ws_size,
                              hipStream_t stream) {
  const float* inputs = (const float*)d_in[0];
  const float* hx     = (const float*)d_in[1];
  const float* eval   = (const float*)d_in[2];
  const float* w1mu   = (const float*)d_in[3];
  const float* w1ls   = (const float*)d_in[4];
  const float* b1mu   = (const float*)d_in[5];
  const float* b1ls   = (const float*)d_in[6];
  const float* w2mu   = (const float*)d_in[7];
  const float* w2ls   = (const float*)d_in[8];
  const float* b2mu   = (const float*)d_in[9];
  const float* b2ls   = (const float*)d_in[10];
  const float* ew1    = (const float*)d_in[11];
  const float* eb1    = (const float*)d_in[12];
  const float* ew2    = (const float*)d_in[13];
  const float* eb2    = (const float*)d_in[14];
  const int* erow     = (const int*)d_in[15];
  const int* ecol     = (const int*)d_in[16];
  float* out = (float*)d_out;

  char* p = (char*)d_ws;
  short* W1p = (short*)p;                 p += 20480 * 2;   // 8*5*64 bf16x8 frags
  short* W2p = (short*)p;                 p += 10240 * 2;   // 4*5*64
  float* B1  = (float*)p;                 p += 128 * 4;
  float* B2  = (float*)p;                 p += 64 * 4;
  unsigned short* X0  = (unsigned short*)p; p += (size_t)N_NODES * FB * 2;
  unsigned short* X0c = (unsigned short*)p; p += (size_t)N_NODES * FB * 2;
  int* cnt    = (int*)p;                  p += 10016 * 4;
  int* rowptr = (int*)p;                  p += 10016 * 4;
  int* cursor = (int*)p;                  p += 10016 * 4;
  int* cidx   = (int*)p;                  p += NEDGE * 4;
  float* cval = (float*)p;                p += NEDGE * 4;

  pack_kernel<<<16, 256, 0, stream>>>(w1mu, w1ls, ew1, b1mu, b1ls, eb1,
                                      w2mu, w2ls, ew2, b2mu, b2ls, eb2,
                                      W1p, W2p, B1, B2);
  build_x0_kernel<<<(N_NODES * FDIM + 255) / 256, 256, 0, stream>>>(inputs, hx, X0, cnt);
  count_kernel<<<(NEDGE + 255) / 256, 256, 0, stream>>>(erow, cnt);
  scan_kernel<<<1, 1024, 0, stream>>>(cnt, rowptr, cursor);
  fill_kernel<<<(NEDGE + 255) / 256, 256, 0, stream>>>(erow, ecol, eval, cursor, cidx, cval);
  gates_kernel<<<N_NODES, 256, 0, stream>>>(X0, W1p, B1, rowptr, cidx, cval, hx, X0c, out);
  cand_kernel<<<N_NODES, 256, 0, stream>>>(X0c, W2p, B2, rowptr, cidx, cval, hx, out);
}

// Round 4
// 131.884 us; speedup vs baseline: 2.4655x; 1.1384x over previous
//
#include <hip/hip_runtime.h>
#include <cmath>

#define N_NODES 10000
#define UNITS   64
#define IND     2
#define BATCH   16
#define NEDGE   80000
#define FDIM    66            // IND + UNITS
#define OG      128           // 2*UNITS
#define OC      64            // UNITS
#define HXS     (N_NODES*UNITS)
#define INS     (N_NODES*IND)
#define KTILES  5             // ceil(132/32)
#define FQ      17            // f-quads per row (F padded 66->68)
#define CHUNKS  272           // 16*17 u16x4 chunks per row
#define RU      1088          // u16 per row (CHUNKS*4)
#define LDSC    20            // padded fq stride in LDS (covers k<160)

typedef __attribute__((ext_vector_type(8))) short bf16x8;
typedef __attribute__((ext_vector_type(4))) float f32x4;
typedef __attribute__((ext_vector_type(4))) unsigned short u16x4;
typedef __attribute__((ext_vector_type(8))) unsigned short u16x8;

__device__ __forceinline__ unsigned short f2bf(float x) {
  union { float f; unsigned u; } v; v.f = x;
  unsigned r = v.u + 0x7fffu + ((v.u >> 16) & 1u);
  return (unsigned short)(r >> 16);
}
__device__ __forceinline__ float bf2f(unsigned short u) {
  union { unsigned u; float f; } v; v.u = ((unsigned)u) << 16; return v.f;
}

// ------- pack W (fused reparam) into MFMA B-frag lane order + biases + zero cnt -------
// B-frag for mfma_f32_16x16x32_bf16: lane l holds B[k][n], n = nt*16+(l&15),
// k = kt*32 + (l>>4)*8 + j
__global__ void pack_kernel(const float* __restrict__ w1mu, const float* __restrict__ w1ls,
                            const float* __restrict__ ew1,
                            const float* __restrict__ b1mu, const float* __restrict__ b1ls,
                            const float* __restrict__ eb1,
                            const float* __restrict__ w2mu, const float* __restrict__ w2ls,
                            const float* __restrict__ ew2,
                            const float* __restrict__ b2mu, const float* __restrict__ b2ls,
                            const float* __restrict__ eb2,
                            short* __restrict__ W1p, short* __restrict__ W2p,
                            float* __restrict__ B1, float* __restrict__ B2,
                            int* __restrict__ cnt) {
  int i = blockIdx.x * 256 + threadIdx.x;
  if (i < 2560) {
    int l = i & 63, kt = (i >> 6) % KTILES, nt = i / (KTILES * 64);
    int o = nt * 16 + (l & 15);
    bf16x8 fr;
#pragma unroll
    for (int j = 0; j < 8; ++j) {
      int k = kt * 32 + (l >> 4) * 8 + j;
      float w = 0.f;
      if (k < 2 * FDIM) { int idx = k * OG + o; w = w1mu[idx] + __expf(w1ls[idx]) * ew1[idx]; }
      fr[j] = (short)f2bf(w);
    }
    *((bf16x8*)W1p + i) = fr;
  } else if (i < 3840) {
    int i2 = i - 2560;
    int l = i2 & 63, kt = (i2 >> 6) % KTILES, nt = i2 / (KTILES * 64);
    int o = nt * 16 + (l & 15);
    bf16x8 fr;
#pragma unroll
    for (int j = 0; j < 8; ++j) {
      int k = kt * 32 + (l >> 4) * 8 + j;
      float w = 0.f;
      if (k < 2 * FDIM) { int idx = k * OC + o; w = w2mu[idx] + __expf(w2ls[idx]) * ew2[idx]; }
      fr[j] = (short)f2bf(w);
    }
    *((bf16x8*)W2p + i2) = fr;
  } else if (i < 3968) {
    int j = i - 3840; B1[j] = b1mu[j] + __expf(b1ls[j]) * eb1[j];
  } else if (i < 4032) {
    int j = i - 3968; B2[j] = b2mu[j] + __expf(b2ls[j]) * eb2[j];
  } else if (i < 4032 + 10016) {
    cnt[i - 4032] = 0;
  }
}

// ------- build X0 bf16 [N][b:16][fq:17][4] + fused edge count -------
__global__ void build_x0_kernel(const float* __restrict__ inputs, const float* __restrict__ hx,
                                unsigned short* __restrict__ X0,
                                const int* __restrict__ erow, int* __restrict__ cnt) {
  int i = blockIdx.x * 256 + threadIdx.x;
  if (i < NEDGE) atomicAdd(&cnt[erow[i]], 1);
  if (i >= N_NODES * CHUNKS) return;
  int n = i / CHUNKS;
  int c = i - n * CHUNKS;
  int b = c / FQ;
  int fq = c - b * FQ;
  float v0, v1, v2, v3;
  if (fq == 0) {
    const float* ip = inputs + (size_t)b * INS + n * IND;
    const float* hp = hx + (size_t)b * HXS + n * UNITS;
    v0 = ip[0]; v1 = ip[1]; v2 = hp[0]; v3 = hp[1];
  } else if (fq < 16) {
    const float* hp = hx + (size_t)b * HXS + n * UNITS + fq * 4 - 2;
    v0 = hp[0]; v1 = hp[1]; v2 = hp[2]; v3 = hp[3];
  } else {
    const float* hp = hx + (size_t)b * HXS + n * UNITS + 62;
    v0 = hp[0]; v1 = hp[1]; v2 = 0.f; v3 = 0.f;
  }
  u16x4 o4;
  o4[0] = f2bf(v0); o4[1] = f2bf(v1); o4[2] = f2bf(v2); o4[3] = f2bf(v3);
  *reinterpret_cast<u16x4*>(X0 + (size_t)i * 4) = o4;
}

// ------- fast scan: 1024 thr, 10 serial each + wave shfl scan -------
__global__ void scan_kernel(const int* __restrict__ cnt, int* __restrict__ rowptr,
                            int* __restrict__ cursor) {
  int t = threadIdx.x;
  int base = t * 10;
  int v[10]; int sum = 0;
#pragma unroll
  for (int j = 0; j < 10; ++j) {
    int idx = base + j;
    int x = (idx < N_NODES) ? cnt[idx] : 0;
    v[j] = sum; sum += x;
  }
  int inc = sum;
  int lane = t & 63, wid = t >> 6;
#pragma unroll
  for (int d = 1; d < 64; d <<= 1) {
    int o = __shfl_up(inc, d, 64);
    if (lane >= d) inc += o;
  }
  __shared__ int wsum[16];
  if (lane == 63) wsum[wid] = inc;
  __syncthreads();
  if (t == 0) {
    int a = 0;
#pragma unroll
    for (int k = 0; k < 16; ++k) { int x = wsum[k]; wsum[k] = a; a += x; }
  }
  __syncthreads();
  int off = wsum[wid] + (inc - sum);
#pragma unroll
  for (int j = 0; j < 10; ++j) {
    int idx = base + j;
    if (idx < N_NODES) { int val = off + v[j]; rowptr[idx] = val; cursor[idx] = val; }
    else if (idx == N_NODES) rowptr[N_NODES] = off + v[j];
  }
}

__global__ void fill_kernel(const int* __restrict__ erow, const int* __restrict__ ecol,
                            const float* __restrict__ eval, int* __restrict__ cursor,
                            int* __restrict__ cidx, float* __restrict__ cval) {
  int i = blockIdx.x * 256 + threadIdx.x;
  if (i >= NEDGE) return;
  int r = erow[i];
  int p = atomicAdd(&cursor[r], 1);
  cidx[p] = ecol[i];
  cval[p] = eval[i];
}

// ------- gather: own row + CSR-gathered x1, interleaved into LDS Y[b][fq'][8] -------
__device__ __forceinline__ void gather_node(const unsigned short* __restrict__ X,
                                            const int* __restrict__ rowptr,
                                            const int* __restrict__ cidx,
                                            const float* __restrict__ cval,
                                            int n, int t, unsigned short* Y) {
  if (t < 48) {                       // zero LDS pads fq' 17..19
    int b = t / 3, fqp = 17 + (t - (t / 3) * 3);
    u16x8 z = {0, 0, 0, 0, 0, 0, 0, 0};
    *reinterpret_cast<u16x8*>(Y + (b * LDSC + fqp) * 8) = z;
  }
  const unsigned short* xrow = X + (size_t)n * RU;
  const int c = t;
  u16x4 own = *reinterpret_cast<const u16x4*>(xrow + c * 4);
  const bool extra = t < (CHUNKS - 256);
  const int c2 = 256 + t;
  u16x4 own2 = {0, 0, 0, 0};
  if (extra) own2 = *reinterpret_cast<const u16x4*>(xrow + c2 * 4);

  float g[4] = {0.f, 0.f, 0.f, 0.f}, ge[4] = {0.f, 0.f, 0.f, 0.f};
  int e = rowptr[n], e1 = rowptr[n + 1];
  for (; e + 4 <= e1; e += 4) {
    int m0 = cidx[e], m1 = cidx[e + 1], m2 = cidx[e + 2], m3 = cidx[e + 3];
    float v0 = cval[e], v1 = cval[e + 1], v2 = cval[e + 2], v3 = cval[e + 3];
    const unsigned short* r0 = X + (size_t)m0 * RU;
    const unsigned short* r1 = X + (size_t)m1 * RU;
    const unsigned short* r2 = X + (size_t)m2 * RU;
    const unsigned short* r3 = X + (size_t)m3 * RU;
    u16x4 A0 = *reinterpret_cast<const u16x4*>(r0 + c * 4);
    u16x4 A1 = *reinterpret_cast<const u16x4*>(r1 + c * 4);
    u16x4 A2 = *reinterpret_cast<const u16x4*>(r2 + c * 4);
    u16x4 A3 = *reinterpret_cast<const u16x4*>(r3 + c * 4);
    if (extra) {
      u16x4 E0 = *reinterpret_cast<const u16x4*>(r0 + c2 * 4);
      u16x4 E1 = *reinterpret_cast<const u16x4*>(r1 + c2 * 4);
      u16x4 E2 = *reinterpret_cast<const u16x4*>(r2 + c2 * 4);
      u16x4 E3 = *reinterpret_cast<const u16x4*>(r3 + c2 * 4);
#pragma unroll
      for (int j = 0; j < 4; ++j)
        ge[j] += v0 * bf2f(E0[j]) + v1 * bf2f(E1[j]) + v2 * bf2f(E2[j]) + v3 * bf2f(E3[j]);
    }
#pragma unroll
    for (int j = 0; j < 4; ++j)
      g[j] += v0 * bf2f(A0[j]) + v1 * bf2f(A1[j]) + v2 * bf2f(A2[j]) + v3 * bf2f(A3[j]);
  }
  for (; e < e1; ++e) {
    int m0 = cidx[e];
    float v0 = cval[e];
    const unsigned short* r0 = X + (size_t)m0 * RU;
    u16x4 A0 = *reinterpret_cast<const u16x4*>(r0 + c * 4);
    if (extra) {
      u16x4 E0 = *reinterpret_cast<const u16x4*>(r0 + c2 * 4);
#pragma unroll
      for (int j = 0; j < 4; ++j) ge[j] += v0 * bf2f(E0[j]);
    }
#pragma unroll
    for (int j = 0; j < 4; ++j) g[j] += v0 * bf2f(A0[j]);
  }
  int b = c / FQ, fq = c - (c / FQ) * FQ;
  u16x8 wv;
#pragma unroll
  for (int j = 0; j < 4; ++j) { wv[2 * j] = own[j]; wv[2 * j + 1] = f2bf(g[j]); }
  *reinterpret_cast<u16x8*>(Y + (b * LDSC + fq) * 8) = wv;
  if (extra) {
    u16x8 wv2;
#pragma unroll
    for (int j = 0; j < 4; ++j) { wv2[2 * j] = own2[j]; wv2[2 * j + 1] = f2bf(ge[j]); }
    *reinterpret_cast<u16x8*>(Y + (15 * LDSC + (t + 1)) * 8) = wv2;   // c2: b=15, fq=t+1
  }
  __syncthreads();
}

// A-frag: lane (ml,s) kt reads 16B = (x0[f0],x1[f0],...,x0[f0+3],x1[f0+3]), f0=kt*16+s*4
__device__ __forceinline__ void build_afrag(const unsigned short* Y, int ml, int s, bf16x8* af) {
#pragma unroll
  for (int kt = 0; kt < KTILES; ++kt)
    af[kt] = *reinterpret_cast<const bf16x8*>(Y + (ml * LDSC + kt * 4 + s) * 8);
}

// ------- gates: gconv1 (MFMA) + sigmoid; r*hx -> X0c (bf16), u -> ubf -------
__global__ __launch_bounds__(256) void gates_kernel(
    const unsigned short* __restrict__ X0, const short* __restrict__ W1p,
    const float* __restrict__ B1,
    const int* __restrict__ rowptr, const int* __restrict__ cidx, const float* __restrict__ cval,
    const float* __restrict__ hx,
    unsigned short* __restrict__ X0c, unsigned short* __restrict__ ubf) {
  __shared__ __align__(16) unsigned short Y[16 * LDSC * 8];
  int n = blockIdx.x, t = threadIdx.x;
  gather_node(X0, rowptr, cidx, cval, n, t, Y);

  int lane = t & 63, w = t >> 6, ml = lane & 15, s = lane >> 4;
  bf16x8 af[KTILES];
  build_afrag(Y, ml, s, af);

  const bf16x8* Wp = (const bf16x8*)W1p;
#pragma unroll
  for (int q = 0; q < 2; ++q) {
    int nt = w * 2 + q;
    f32x4 acc = {0.f, 0.f, 0.f, 0.f};
#pragma unroll
    for (int kt = 0; kt < KTILES; ++kt)
      acc = __builtin_amdgcn_mfma_f32_16x16x32_bf16(af[kt], Wp[(nt * KTILES + kt) * 64 + lane],
                                                    acc, 0, 0, 0);
    int o = nt * 16 + ml;           // output col; rows = batch s*4+r
    float bias = B1[o];
    if (o < UNITS) {
      int f = o + IND, fq = f >> 2, fr = f & 3;
#pragma unroll
      for (int r = 0; r < 4; ++r) {
        int b = s * 4 + r;
        float sg = 1.f / (1.f + __expf(-(acc[r] + bias)));
        float rh = sg * hx[(size_t)b * HXS + n * UNITS + o];
        X0c[(size_t)n * RU + (b * FQ + fq) * 4 + fr] = f2bf(rh);
      }
    } else {
      int ou = o - UNITS;
#pragma unroll
      for (int r = 0; r < 4; ++r) {
        int b = s * 4 + r;
        float sg = 1.f / (1.f + __expf(-(acc[r] + bias)));
        ubf[(size_t)b * HXS + n * UNITS + ou] = f2bf(sg);
      }
    }
  }
  // inputs (f=0,1) into X0c; pad f=66,67 zeros
  if (t < 32) {
    int b = t >> 1, f = t & 1;
    X0c[(size_t)n * RU + (b * FQ) * 4 + f] = Y[(b * LDSC) * 8 + f * 2];
  }
  if (t < 16) {
    *reinterpret_cast<unsigned*>(X0c + (size_t)n * RU + (t * FQ + 16) * 4 + 2) = 0u;
  }
}

// ------- candidate: gconv2 (MFMA) + tanh + GRU combine -------
__global__ __launch_bounds__(256) void cand_kernel(
    const unsigned short* __restrict__ X0c, const short* __restrict__ W2p,
    const float* __restrict__ B2,
    const int* __restrict__ rowptr, const int* __restrict__ cidx, const float* __restrict__ cval,
    const float* __restrict__ hx, const unsigned short* __restrict__ ubf,
    float* __restrict__ out) {
  __shared__ __align__(16) unsigned short Y[16 * LDSC * 8];
  int n = blockIdx.x, t = threadIdx.x;
  gather_node(X0c, rowptr, cidx, cval, n, t, Y);

  int lane = t & 63, w = t >> 6, ml = lane & 15, s = lane >> 4;
  bf16x8 af[KTILES];
  build_afrag(Y, ml, s, af);

  const bf16x8* Wp = (const bf16x8*)W2p;
  f32x4 acc = {0.f, 0.f, 0.f, 0.f};
#pragma unroll
  for (int kt = 0; kt < KTILES; ++kt)
    acc = __builtin_amdgcn_mfma_f32_16x16x32_bf16(af[kt], Wp[(w * KTILES + kt) * 64 + lane],
                                                  acc, 0, 0, 0);
  int o = w * 16 + ml;
  float bias = B2[o];
#pragma unroll
  for (int r = 0; r < 4; ++r) {
    int b = s * 4 + r;
    size_t idx = (size_t)b * HXS + n * UNITS + o;
    float x = acc[r] + bias;
    float c = 1.f - 2.f / (__expf(2.f * x) + 1.f);   // tanh
    float u = bf2f(ubf[idx]);
    float h = hx[idx];
    out[idx] = u * h + (1.f - u) * c;
  }
}

extern "C" void kernel_launch(void* const* d_in, const int* in_sizes, int n_in,
                              void* d_out, int out_size, void* d_ws, size_t ws_size,
                              hipStream_t stream) {
  const float* inputs = (const float*)d_in[0];
  const float* hx     = (const float*)d_in[1];
  const float* eval   = (const float*)d_in[2];
  const float* w1mu   = (const float*)d_in[3];
  const float* w1ls   = (const float*)d_in[4];
  const float* b1mu   = (const float*)d_in[5];
  const float* b1ls   = (const float*)d_in[6];
  const float* w2mu   = (const float*)d_in[7];
  const float* w2ls   = (const float*)d_in[8];
  const float* b2mu   = (const float*)d_in[9];
  const float* b2ls   = (const float*)d_in[10];
  const float* ew1    = (const float*)d_in[11];
  const float* eb1    = (const float*)d_in[12];
  const float* ew2    = (const float*)d_in[13];
  const float* eb2    = (const float*)d_in[14];
  const int* erow     = (const int*)d_in[15];
  const int* ecol     = (const int*)d_in[16];
  float* out = (float*)d_out;

  char* p = (char*)d_ws;
  short* W1p = (short*)p;                   p += 20480 * 2;
  short* W2p = (short*)p;                   p += 10240 * 2;
  float* B1  = (float*)p;                   p += 128 * 4;
  float* B2  = (float*)p;                   p += 64 * 4;
  unsigned short* X0  = (unsigned short*)p; p += (size_t)N_NODES * RU * 2;
  unsigned short* X0c = (unsigned short*)p; p += (size_t)N_NODES * RU * 2;
  unsigned short* ubf = (unsigned short*)p; p += (size_t)BATCH * HXS * 2;
  int* cnt    = (int*)p;                    p += 10016 * 4;
  int* rowptr = (int*)p;                    p += 10016 * 4;
  int* cursor = (int*)p;                    p += 10016 * 4;
  int* cidx   = (int*)p;                    p += NEDGE * 4;
  float* cval = (float*)p;                  p += NEDGE * 4;

  pack_kernel<<<55, 256, 0, stream>>>(w1mu, w1ls, ew1, b1mu, b1ls, eb1,
                                      w2mu, w2ls, ew2, b2mu, b2ls, eb2,
                                      W1p, W2p, B1, B2, cnt);
  build_x0_kernel<<<(N_NODES * CHUNKS + 255) / 256, 256, 0, stream>>>(inputs, hx, X0, erow, cnt);
  scan_kernel<<<1, 1024, 0, stream>>>(cnt, rowptr, cursor);
  fill_kernel<<<(NEDGE + 255) / 256, 256, 0, stream>>>(erow, ecol, eval, cursor, cidx, cval);
  gates_kernel<<<N_NODES, 256, 0, stream>>>(X0, W1p, B1, rowptr, cidx, cval, hx, X0c, ubf);
  cand_kernel<<<N_NODES, 256, 0, stream>>>(X0c, W2p, B2, rowptr, cidx, cval, hx, ubf, out);
}

// Round 5
// 126.256 us; speedup vs baseline: 2.5753x; 1.0446x over previous
//
#include <hip/hip_runtime.h>
#include <cmath>

#define N_NODES 10000
#define UNITS   64
#define IND     2
#define BATCH   16
#define NEDGE   80000
#define FDIM    66            // IND + UNITS
#define OG      128           // 2*UNITS
#define OC      64            // UNITS
#define HXS     (N_NODES*UNITS)
#define INS     (N_NODES*IND)
#define KTILES  5             // ceil(132/32)
#define FQ      17            // f-quads per row (F padded 66->68)
#define CHUNKS  272           // 16*17 u16x4 chunks per row
#define RU      1088          // u16 per row (CHUNKS*4)
#define LDSC    21            // padded fq stride in LDS (bank-conflict-free reads)

typedef __attribute__((ext_vector_type(8))) short bf16x8;
typedef __attribute__((ext_vector_type(4))) float f32x4;
typedef __attribute__((ext_vector_type(4))) unsigned short u16x4;
typedef __attribute__((ext_vector_type(8))) unsigned short u16x8;

__device__ __forceinline__ unsigned short f2bf(float x) {
  union { float f; unsigned u; } v; v.f = x;
  unsigned r = v.u + 0x7fffu + ((v.u >> 16) & 1u);
  return (unsigned short)(r >> 16);
}
__device__ __forceinline__ float bf2f(unsigned short u) {
  union { unsigned u; float f; } v; v.u = ((unsigned)u) << 16; return v.f;
}

// ------- pack W (fused reparam) into MFMA B-frag lane order + biases + zero cnt -------
// B-frag for mfma_f32_16x16x32_bf16: lane l holds B[k][n], n = nt*16+(l&15),
// k = kt*32 + (l>>4)*8 + j
__global__ void pack_kernel(const float* __restrict__ w1mu, const float* __restrict__ w1ls,
                            const float* __restrict__ ew1,
                            const float* __restrict__ b1mu, const float* __restrict__ b1ls,
                            const float* __restrict__ eb1,
                            const float* __restrict__ w2mu, const float* __restrict__ w2ls,
                            const float* __restrict__ ew2,
                            const float* __restrict__ b2mu, const float* __restrict__ b2ls,
                            const float* __restrict__ eb2,
                            short* __restrict__ W1p, short* __restrict__ W2p,
                            float* __restrict__ B1, float* __restrict__ B2,
                            int* __restrict__ cnt) {
  int i = blockIdx.x * 256 + threadIdx.x;
  if (i < 2560) {
    int l = i & 63, kt = (i >> 6) % KTILES, nt = i / (KTILES * 64);
    int o = nt * 16 + (l & 15);
    bf16x8 fr;
#pragma unroll
    for (int j = 0; j < 8; ++j) {
      int k = kt * 32 + (l >> 4) * 8 + j;
      float w = 0.f;
      if (k < 2 * FDIM) { int idx = k * OG + o; w = w1mu[idx] + __expf(w1ls[idx]) * ew1[idx]; }
      fr[j] = (short)f2bf(w);
    }
    *((bf16x8*)W1p + i) = fr;
  } else if (i < 3840) {
    int i2 = i - 2560;
    int l = i2 & 63, kt = (i2 >> 6) % KTILES, nt = i2 / (KTILES * 64);
    int o = nt * 16 + (l & 15);
    bf16x8 fr;
#pragma unroll
    for (int j = 0; j < 8; ++j) {
      int k = kt * 32 + (l >> 4) * 8 + j;
      float w = 0.f;
      if (k < 2 * FDIM) { int idx = k * OC + o; w = w2mu[idx] + __expf(w2ls[idx]) * ew2[idx]; }
      fr[j] = (short)f2bf(w);
    }
    *((bf16x8*)W2p + i2) = fr;
  } else if (i < 3968) {
    int j = i - 3840; B1[j] = b1mu[j] + __expf(b1ls[j]) * eb1[j];
  } else if (i < 4032) {
    int j = i - 3968; B2[j] = b2mu[j] + __expf(b2ls[j]) * eb2[j];
  } else if (i < 4032 + 10016) {
    cnt[i - 4032] = 0;
  }
}

// ------- build X0 bf16 [N][b:16][fq:17][4] + fused edge count -------
__global__ void build_x0_kernel(const float* __restrict__ inputs, const float* __restrict__ hx,
                                unsigned short* __restrict__ X0,
                                const int* __restrict__ erow, int* __restrict__ cnt) {
  int i = blockIdx.x * 256 + threadIdx.x;
  if (i < NEDGE) atomicAdd(&cnt[erow[i]], 1);
  if (i >= N_NODES * CHUNKS) return;
  int n = i / CHUNKS;
  int c = i - n * CHUNKS;
  int b = c / FQ;
  int fq = c - b * FQ;
  float v0, v1, v2, v3;
  if (fq == 0) {
    const float* ip = inputs + (size_t)b * INS + n * IND;
    const float* hp = hx + (size_t)b * HXS + n * UNITS;
    v0 = ip[0]; v1 = ip[1]; v2 = hp[0]; v3 = hp[1];
  } else if (fq < 16) {
    const float* hp = hx + (size_t)b * HXS + n * UNITS + fq * 4 - 2;
    v0 = hp[0]; v1 = hp[1]; v2 = hp[2]; v3 = hp[3];
  } else {
    const float* hp = hx + (size_t)b * HXS + n * UNITS + 62;
    v0 = hp[0]; v1 = hp[1]; v2 = 0.f; v3 = 0.f;
  }
  u16x4 o4;
  o4[0] = f2bf(v0); o4[1] = f2bf(v1); o4[2] = f2bf(v2); o4[3] = f2bf(v3);
  *reinterpret_cast<u16x4*>(X0 + (size_t)i * 4) = o4;
}

// ------- fast scan: 1024 thr, 10 serial each + wave shfl scan -------
__global__ void scan_kernel(const int* __restrict__ cnt, int* __restrict__ rowptr,
                            int* __restrict__ cursor) {
  int t = threadIdx.x;
  int base = t * 10;
  int v[10]; int sum = 0;
#pragma unroll
  for (int j = 0; j < 10; ++j) {
    int idx = base + j;
    int x = (idx < N_NODES) ? cnt[idx] : 0;
    v[j] = sum; sum += x;
  }
  int inc = sum;
  int lane = t & 63, wid = t >> 6;
#pragma unroll
  for (int d = 1; d < 64; d <<= 1) {
    int o = __shfl_up(inc, d, 64);
    if (lane >= d) inc += o;
  }
  __shared__ int wsum[16];
  if (lane == 63) wsum[wid] = inc;
  __syncthreads();
  if (t == 0) {
    int a = 0;
#pragma unroll
    for (int k = 0; k < 16; ++k) { int x = wsum[k]; wsum[k] = a; a += x; }
  }
  __syncthreads();
  int off = wsum[wid] + (inc - sum);
#pragma unroll
  for (int j = 0; j < 10; ++j) {
    int idx = base + j;
    if (idx < N_NODES) { int val = off + v[j]; rowptr[idx] = val; cursor[idx] = val; }
    else if (idx == N_NODES) rowptr[N_NODES] = off + v[j];
  }
}

__global__ void fill_kernel(const int* __restrict__ erow, const int* __restrict__ ecol,
                            const float* __restrict__ eval, int* __restrict__ cursor,
                            int* __restrict__ cidx, float* __restrict__ cval) {
  int i = blockIdx.x * 256 + threadIdx.x;
  if (i >= NEDGE) return;
  int r = erow[i];
  int p = atomicAdd(&cursor[r], 1);
  cidx[p] = ecol[i];
  cval[p] = eval[i];
}

// ------- gather: own row + CSR-gathered x1, interleaved into LDS Y[b][fq'][8] -------
__device__ __forceinline__ void gather_node(const unsigned short* __restrict__ X,
                                            const int* __restrict__ rowptr,
                                            const int* __restrict__ cidx,
                                            const float* __restrict__ cval,
                                            int n, int t, unsigned short* Y) {
  if (t < 48) {                       // zero LDS pads fq' 17..19
    int b = t / 3, fqp = 17 + (t - (t / 3) * 3);
    u16x8 z = {0, 0, 0, 0, 0, 0, 0, 0};
    *reinterpret_cast<u16x8*>(Y + (b * LDSC + fqp) * 8) = z;
  }
  const unsigned short* xrow = X + (size_t)n * RU;
  const int c = t;
  u16x4 own = *reinterpret_cast<const u16x4*>(xrow + c * 4);
  const bool extra = t < (CHUNKS - 256);
  const int c2 = 256 + t;
  u16x4 own2 = {0, 0, 0, 0};
  if (extra) own2 = *reinterpret_cast<const u16x4*>(xrow + c2 * 4);

  float g[4] = {0.f, 0.f, 0.f, 0.f}, ge[4] = {0.f, 0.f, 0.f, 0.f};
  int e = rowptr[n], e1 = rowptr[n + 1];
  for (; e + 4 <= e1; e += 4) {
    int m0 = cidx[e], m1 = cidx[e + 1], m2 = cidx[e + 2], m3 = cidx[e + 3];
    float v0 = cval[e], v1 = cval[e + 1], v2 = cval[e + 2], v3 = cval[e + 3];
    const unsigned short* r0 = X + (size_t)m0 * RU;
    const unsigned short* r1 = X + (size_t)m1 * RU;
    const unsigned short* r2 = X + (size_t)m2 * RU;
    const unsigned short* r3 = X + (size_t)m3 * RU;
    u16x4 A0 = *reinterpret_cast<const u16x4*>(r0 + c * 4);
    u16x4 A1 = *reinterpret_cast<const u16x4*>(r1 + c * 4);
    u16x4 A2 = *reinterpret_cast<const u16x4*>(r2 + c * 4);
    u16x4 A3 = *reinterpret_cast<const u16x4*>(r3 + c * 4);
    if (extra) {
      u16x4 E0 = *reinterpret_cast<const u16x4*>(r0 + c2 * 4);
      u16x4 E1 = *reinterpret_cast<const u16x4*>(r1 + c2 * 4);
      u16x4 E2 = *reinterpret_cast<const u16x4*>(r2 + c2 * 4);
      u16x4 E3 = *reinterpret_cast<const u16x4*>(r3 + c2 * 4);
#pragma unroll
      for (int j = 0; j < 4; ++j)
        ge[j] += v0 * bf2f(E0[j]) + v1 * bf2f(E1[j]) + v2 * bf2f(E2[j]) + v3 * bf2f(E3[j]);
    }
#pragma unroll
    for (int j = 0; j < 4; ++j)
      g[j] += v0 * bf2f(A0[j]) + v1 * bf2f(A1[j]) + v2 * bf2f(A2[j]) + v3 * bf2f(A3[j]);
  }
  for (; e < e1; ++e) {
    int m0 = cidx[e];
    float v0 = cval[e];
    const unsigned short* r0 = X + (size_t)m0 * RU;
    u16x4 A0 = *reinterpret_cast<const u16x4*>(r0 + c * 4);
    if (extra) {
      u16x4 E0 = *reinterpret_cast<const u16x4*>(r0 + c2 * 4);
#pragma unroll
      for (int j = 0; j < 4; ++j) ge[j] += v0 * bf2f(E0[j]);
    }
#pragma unroll
    for (int j = 0; j < 4; ++j) g[j] += v0 * bf2f(A0[j]);
  }
  int b = c / FQ, fq = c - (c / FQ) * FQ;
  u16x8 wv;
#pragma unroll
  for (int j = 0; j < 4; ++j) { wv[2 * j] = own[j]; wv[2 * j + 1] = f2bf(g[j]); }
  *reinterpret_cast<u16x8*>(Y + (b * LDSC + fq) * 8) = wv;
  if (extra) {
    u16x8 wv2;
#pragma unroll
    for (int j = 0; j < 4; ++j) { wv2[2 * j] = own2[j]; wv2[2 * j + 1] = f2bf(ge[j]); }
    *reinterpret_cast<u16x8*>(Y + (15 * LDSC + (t + 1)) * 8) = wv2;   // c2: b=15, fq=t+1
  }
  __syncthreads();
}

// A-frag: lane (ml,s) kt reads 16B = (x0[f0],x1[f0],...,x0[f0+3],x1[f0+3]), f0=kt*16+s*4
__device__ __forceinline__ void build_afrag(const unsigned short* Y, int ml, int s, bf16x8* af) {
#pragma unroll
  for (int kt = 0; kt < KTILES; ++kt)
    af[kt] = *reinterpret_cast<const bf16x8*>(Y + (ml * LDSC + kt * 4 + s) * 8);
}

// ------- gates: gconv1 (MFMA) + sigmoid; r*h -> X0c (bf16), {u, u*h} -> upk -------
__global__ __launch_bounds__(256) void gates_kernel(
    const unsigned short* __restrict__ X0, const short* __restrict__ W1p,
    const float* __restrict__ B1,
    const int* __restrict__ rowptr, const int* __restrict__ cidx, const float* __restrict__ cval,
    unsigned short* __restrict__ X0c, unsigned* __restrict__ upk) {
  __shared__ __align__(16) unsigned short Y[16 * LDSC * 8];
  int n = blockIdx.x, t = threadIdx.x;
  gather_node(X0, rowptr, cidx, cval, n, t, Y);

  int lane = t & 63, w = t >> 6, ml = lane & 15, s = lane >> 4;
  bf16x8 af[KTILES];
  build_afrag(Y, ml, s, af);

  const bf16x8* Wp = (const bf16x8*)W1p;
#pragma unroll
  for (int q = 0; q < 2; ++q) {
    int nt = w * 2 + q;
    f32x4 acc = {0.f, 0.f, 0.f, 0.f};
#pragma unroll
    for (int kt = 0; kt < KTILES; ++kt)
      acc = __builtin_amdgcn_mfma_f32_16x16x32_bf16(af[kt], Wp[(nt * KTILES + kt) * 64 + lane],
                                                    acc, 0, 0, 0);
    int o = nt * 16 + ml;           // output col; rows = batch s*4+r
    float bias = B1[o];
    if (o < UNITS) {
      int f = o + IND, fqi = f >> 2, fr = f & 3;
#pragma unroll
      for (int r = 0; r < 4; ++r) {
        int b = s * 4 + r;
        float h = bf2f(Y[(b * LDSC + fqi) * 8 + 2 * fr]);   // h (bf16) from staged own-row
        float sg = 1.f / (1.f + __expf(-(acc[r] + bias)));
        X0c[(size_t)n * RU + (b * FQ + fqi) * 4 + fr] = f2bf(sg * h);
      }
    } else {
      int ou = o - UNITS;
      int f = ou + IND, fqi = f >> 2, fr = f & 3;
#pragma unroll
      for (int r = 0; r < 4; ++r) {
        int b = s * 4 + r;
        float h = bf2f(Y[(b * LDSC + fqi) * 8 + 2 * fr]);
        float u = 1.f / (1.f + __expf(-(acc[r] + bias)));
        unsigned pk = (unsigned)f2bf(u) | ((unsigned)f2bf(u * h) << 16);
        upk[(size_t)b * HXS + n * UNITS + ou] = pk;
      }
    }
  }
  // inputs (f=0,1) into X0c; pad f=66,67 zeros
  if (t < 32) {
    int b = t >> 1, f = t & 1;
    X0c[(size_t)n * RU + (b * FQ) * 4 + f] = Y[(b * LDSC) * 8 + f * 2];
  }
  if (t < 16) {
    *reinterpret_cast<unsigned*>(X0c + (size_t)n * RU + (t * FQ + 16) * 4 + 2) = 0u;
  }
}

// ------- candidate: gconv2 (MFMA) + tanh + GRU combine (out = uh + (1-u)*c) -------
__global__ __launch_bounds__(256) void cand_kernel(
    const unsigned short* __restrict__ X0c, const short* __restrict__ W2p,
    const float* __restrict__ B2,
    const int* __restrict__ rowptr, const int* __restrict__ cidx, const float* __restrict__ cval,
    const unsigned* __restrict__ upk, float* __restrict__ out) {
  __shared__ __align__(16) unsigned short Y[16 * LDSC * 8];
  int n = blockIdx.x, t = threadIdx.x;
  gather_node(X0c, rowptr, cidx, cval, n, t, Y);

  int lane = t & 63, w = t >> 6, ml = lane & 15, s = lane >> 4;
  bf16x8 af[KTILES];
  build_afrag(Y, ml, s, af);

  const bf16x8* Wp = (const bf16x8*)W2p;
  f32x4 acc = {0.f, 0.f, 0.f, 0.f};
#pragma unroll
  for (int kt = 0; kt < KTILES; ++kt)
    acc = __builtin_amdgcn_mfma_f32_16x16x32_bf16(af[kt], Wp[(w * KTILES + kt) * 64 + lane],
                                                  acc, 0, 0, 0);
  int o = w * 16 + ml;
  float bias = B2[o];
#pragma unroll
  for (int r = 0; r < 4; ++r) {
    int b = s * 4 + r;
    size_t idx = (size_t)b * HXS + n * UNITS + o;
    float x = acc[r] + bias;
    float c = 1.f - 2.f / (__expf(2.f * x) + 1.f);   // tanh
    unsigned pk = upk[idx];
    float u = bf2f((unsigned short)(pk & 0xffffu));
    float uh = bf2f((unsigned short)(pk >> 16));
    out[idx] = uh + (1.f - u) * c;
  }
}

extern "C" void kernel_launch(void* const* d_in, const int* in_sizes, int n_in,
                              void* d_out, int out_size, void* d_ws, size_t ws_size,
                              hipStream_t stream) {
  const float* inputs = (const float*)d_in[0];
  const float* hx     = (const float*)d_in[1];
  const float* eval   = (const float*)d_in[2];
  const float* w1mu   = (const float*)d_in[3];
  const float* w1ls   = (const float*)d_in[4];
  const float* b1mu   = (const float*)d_in[5];
  const float* b1ls   = (const float*)d_in[6];
  const float* w2mu   = (const float*)d_in[7];
  const float* w2ls   = (const float*)d_in[8];
  const float* b2mu   = (const float*)d_in[9];
  const float* b2ls   = (const float*)d_in[10];
  const float* ew1    = (const float*)d_in[11];
  const float* eb1    = (const float*)d_in[12];
  const float* ew2    = (const float*)d_in[13];
  const float* eb2    = (const float*)d_in[14];
  const int* erow     = (const int*)d_in[15];
  const int* ecol     = (const int*)d_in[16];
  float* out = (float*)d_out;

  char* p = (char*)d_ws;
  short* W1p = (short*)p;                   p += 20480 * 2;
  short* W2p = (short*)p;                   p += 10240 * 2;
  float* B1  = (float*)p;                   p += 128 * 4;
  float* B2  = (float*)p;                   p += 64 * 4;
  unsigned short* X0  = (unsigned short*)p; p += (size_t)N_NODES * RU * 2;
  unsigned short* X0c = (unsigned short*)p; p += (size_t)N_NODES * RU * 2;
  unsigned* upk = (unsigned*)p;             p += (size_t)BATCH * HXS * 4;
  int* cnt    = (int*)p;                    p += 10016 * 4;
  int* rowptr = (int*)p;                    p += 10016 * 4;
  int* cursor = (int*)p;                    p += 10016 * 4;
  int* cidx   = (int*)p;                    p += NEDGE * 4;
  float* cval = (float*)p;                  p += NEDGE * 4;

  pack_kernel<<<55, 256, 0, stream>>>(w1mu, w1ls, ew1, b1mu, b1ls, eb1,
                                      w2mu, w2ls, ew2, b2mu, b2ls, eb2,
                                      W1p, W2p, B1, B2, cnt);
  build_x0_kernel<<<(N_NODES * CHUNKS + 255) / 256, 256, 0, stream>>>(inputs, hx, X0, erow, cnt);
  scan_kernel<<<1, 1024, 0, stream>>>(cnt, rowptr, cursor);
  fill_kernel<<<(NEDGE + 255) / 256, 256, 0, stream>>>(erow, ecol, eval, cursor, cidx, cval);
  gates_kernel<<<N_NODES, 256, 0, stream>>>(X0, W1p, B1, rowptr, cidx, cval, X0c, upk);
  cand_kernel<<<N_NODES, 256, 0, stream>>>(X0c, W2p, B2, rowptr, cidx, cval, upk, out);
}

// Round 6
// 113.479 us; speedup vs baseline: 2.8653x; 1.1126x over previous
//
#include <hip/hip_runtime.h>
#include <cmath>

#define N_NODES 10000
#define UNITS   64
#define IND     2
#define BATCH   16
#define NEDGE   80000
#define FDIM    66            // IND + UNITS
#define OG      128           // 2*UNITS
#define OC      64            // UNITS
#define HXS     (N_NODES*UNITS)
#define INS     (N_NODES*IND)
#define KTILES  5             // ceil(132/32)
#define FQ      17            // f-quads per row (F padded 66->68)
#define CHUNKS  272           // 16*17 quads per row
#define RU      1088          // u16 per bf16 row
#define LDSC    21            // padded fq stride in LDS

typedef __attribute__((ext_vector_type(8))) short bf16x8;
typedef __attribute__((ext_vector_type(4))) float f32x4;
typedef __attribute__((ext_vector_type(2))) float f32x2;
typedef __attribute__((ext_vector_type(4))) unsigned short u16x4;
typedef __attribute__((ext_vector_type(8))) unsigned short u16x8;

__device__ __forceinline__ unsigned short f2bf(float x) {
  union { float f; unsigned u; } v; v.f = x;
  unsigned r = v.u + 0x7fffu + ((v.u >> 16) & 1u);
  return (unsigned short)(r >> 16);
}
__device__ __forceinline__ float bf2f(unsigned short u) {
  union { unsigned u; float f; } v; v.u = ((unsigned)u) << 16; return v.f;
}
__device__ __forceinline__ unsigned pk4fp8(float a, float b, float c, float d) {
  int v = __builtin_amdgcn_cvt_pk_fp8_f32(a, b, 0, false);
  v = __builtin_amdgcn_cvt_pk_fp8_f32(c, d, v, true);
  return (unsigned)v;
}
__device__ __forceinline__ unsigned char f2fp8(float a) {
  return (unsigned char)(__builtin_amdgcn_cvt_pk_fp8_f32(a, 0.f, 0, false) & 0xff);
}

// ------- pack W (fused reparam) into MFMA B-frag lane order + biases + zero cnt -------
__global__ void pack_kernel(const float* __restrict__ w1mu, const float* __restrict__ w1ls,
                            const float* __restrict__ ew1,
                            const float* __restrict__ b1mu, const float* __restrict__ b1ls,
                            const float* __restrict__ eb1,
                            const float* __restrict__ w2mu, const float* __restrict__ w2ls,
                            const float* __restrict__ ew2,
                            const float* __restrict__ b2mu, const float* __restrict__ b2ls,
                            const float* __restrict__ eb2,
                            short* __restrict__ W1p, short* __restrict__ W2p,
                            float* __restrict__ B1, float* __restrict__ B2,
                            int* __restrict__ cnt) {
  int i = blockIdx.x * 256 + threadIdx.x;
  if (i < 2560) {
    int l = i & 63, kt = (i >> 6) % KTILES, nt = i / (KTILES * 64);
    int o = nt * 16 + (l & 15);
    bf16x8 fr;
#pragma unroll
    for (int j = 0; j < 8; ++j) {
      int k = kt * 32 + (l >> 4) * 8 + j;
      float w = 0.f;
      if (k < 2 * FDIM) { int idx = k * OG + o; w = w1mu[idx] + __expf(w1ls[idx]) * ew1[idx]; }
      fr[j] = (short)f2bf(w);
    }
    *((bf16x8*)W1p + i) = fr;
  } else if (i < 3840) {
    int i2 = i - 2560;
    int l = i2 & 63, kt = (i2 >> 6) % KTILES, nt = i2 / (KTILES * 64);
    int o = nt * 16 + (l & 15);
    bf16x8 fr;
#pragma unroll
    for (int j = 0; j < 8; ++j) {
      int k = kt * 32 + (l >> 4) * 8 + j;
      float w = 0.f;
      if (k < 2 * FDIM) { int idx = k * OC + o; w = w2mu[idx] + __expf(w2ls[idx]) * ew2[idx]; }
      fr[j] = (short)f2bf(w);
    }
    *((bf16x8*)W2p + i2) = fr;
  } else if (i < 3968) {
    int j = i - 3840; B1[j] = b1mu[j] + __expf(b1ls[j]) * eb1[j];
  } else if (i < 4032) {
    int j = i - 3968; B2[j] = b2mu[j] + __expf(b2ls[j]) * eb2[j];
  } else if (i < 4032 + 10016) {
    cnt[i - 4032] = 0;
  }
}

// ------- build X0 (bf16) + X8 (fp8 shadow) [N][b:16][fq:17][4] + fused edge count -------
__global__ void build_x0_kernel(const float* __restrict__ inputs, const float* __restrict__ hx,
                                unsigned short* __restrict__ X0, unsigned* __restrict__ X8,
                                const int* __restrict__ erow, int* __restrict__ cnt) {
  int i = blockIdx.x * 256 + threadIdx.x;
  if (i < NEDGE) atomicAdd(&cnt[erow[i]], 1);
  if (i >= N_NODES * CHUNKS) return;
  int n = i / CHUNKS;
  int c = i - n * CHUNKS;
  int b = c / FQ;
  int fq = c - b * FQ;
  float v0, v1, v2, v3;
  if (fq == 0) {
    const float* ip = inputs + (size_t)b * INS + n * IND;
    const float* hp = hx + (size_t)b * HXS + n * UNITS;
    v0 = ip[0]; v1 = ip[1]; v2 = hp[0]; v3 = hp[1];
  } else if (fq < 16) {
    const float* hp = hx + (size_t)b * HXS + n * UNITS + fq * 4 - 2;
    v0 = hp[0]; v1 = hp[1]; v2 = hp[2]; v3 = hp[3];
  } else {
    const float* hp = hx + (size_t)b * HXS + n * UNITS + 62;
    v0 = hp[0]; v1 = hp[1]; v2 = 0.f; v3 = 0.f;
  }
  u16x4 o4;
  o4[0] = f2bf(v0); o4[1] = f2bf(v1); o4[2] = f2bf(v2); o4[3] = f2bf(v3);
  *reinterpret_cast<u16x4*>(X0 + (size_t)i * 4) = o4;
  X8[i] = pk4fp8(v0, v1, v2, v3);
}

// ------- fast scan -------
__global__ void scan_kernel(const int* __restrict__ cnt, int* __restrict__ rowptr,
                            int* __restrict__ cursor) {
  int t = threadIdx.x;
  int base = t * 10;
  int v[10]; int sum = 0;
#pragma unroll
  for (int j = 0; j < 10; ++j) {
    int idx = base + j;
    int x = (idx < N_NODES) ? cnt[idx] : 0;
    v[j] = sum; sum += x;
  }
  int inc = sum;
  int lane = t & 63, wid = t >> 6;
#pragma unroll
  for (int d = 1; d < 64; d <<= 1) {
    int o = __shfl_up(inc, d, 64);
    if (lane >= d) inc += o;
  }
  __shared__ int wsum[16];
  if (lane == 63) wsum[wid] = inc;
  __syncthreads();
  if (t == 0) {
    int a = 0;
#pragma unroll
    for (int k = 0; k < 16; ++k) { int x = wsum[k]; wsum[k] = a; a += x; }
  }
  __syncthreads();
  int off = wsum[wid] + (inc - sum);
#pragma unroll
  for (int j = 0; j < 10; ++j) {
    int idx = base + j;
    if (idx < N_NODES) { int val = off + v[j]; rowptr[idx] = val; cursor[idx] = val; }
    else if (idx == N_NODES) rowptr[N_NODES] = off + v[j];
  }
}

__global__ void fill_kernel(const int* __restrict__ erow, const int* __restrict__ ecol,
                            const float* __restrict__ eval, int* __restrict__ cursor,
                            int* __restrict__ cidx, float* __restrict__ cval) {
  int i = blockIdx.x * 256 + threadIdx.x;
  if (i >= NEDGE) return;
  int r = erow[i];
  int p = atomicAdd(&cursor[r], 1);
  cidx[p] = ecol[i];
  cval[p] = eval[i];
}

// ------- gather: own row (bf16 or fp8) + fp8 CSR gather, interleaved into LDS Y -------
template<bool OWNBF>
__device__ __forceinline__ void gather_node(const unsigned short* __restrict__ XownB,
                                            const unsigned* __restrict__ X8t,
                                            const int* __restrict__ rowptr,
                                            const int* __restrict__ cidx,
                                            const float* __restrict__ cval,
                                            int n, int t, unsigned short* Y) {
  if (t < 48) {                       // zero LDS pads fq' 17..19
    int b = t / 3, fqp = 17 + (t - (t / 3) * 3);
    u16x8 z = {0, 0, 0, 0, 0, 0, 0, 0};
    *reinterpret_cast<u16x8*>(Y + (b * LDSC + fqp) * 8) = z;
  }
  const int c = t, c2 = 256 + t;
  const bool extra = t < (CHUNKS - 256);
  u16x4 own, own2 = {0, 0, 0, 0};
  if (OWNBF) {
    const unsigned short* xrow = XownB + (size_t)n * RU;
    own = *reinterpret_cast<const u16x4*>(xrow + c * 4);
    if (extra) own2 = *reinterpret_cast<const u16x4*>(xrow + c2 * 4);
  } else {
    const unsigned* xrow = X8t + (size_t)n * CHUNKS;
    unsigned wo = xrow[c];
    f32x2 lo = __builtin_amdgcn_cvt_pk_f32_fp8((int)wo, false);
    f32x2 hi = __builtin_amdgcn_cvt_pk_f32_fp8((int)wo, true);
    own[0] = f2bf(lo[0]); own[1] = f2bf(lo[1]); own[2] = f2bf(hi[0]); own[3] = f2bf(hi[1]);
    if (extra) {
      unsigned wo2 = xrow[c2];
      f32x2 lo2 = __builtin_amdgcn_cvt_pk_f32_fp8((int)wo2, false);
      f32x2 hi2 = __builtin_amdgcn_cvt_pk_f32_fp8((int)wo2, true);
      own2[0] = f2bf(lo2[0]); own2[1] = f2bf(lo2[1]); own2[2] = f2bf(hi2[0]); own2[3] = f2bf(hi2[1]);
    }
  }

  float g[4] = {0.f, 0.f, 0.f, 0.f}, ge[4] = {0.f, 0.f, 0.f, 0.f};
  int e = rowptr[n], e1 = rowptr[n + 1];
  for (; e + 4 <= e1; e += 4) {
    int m0 = cidx[e], m1 = cidx[e + 1], m2 = cidx[e + 2], m3 = cidx[e + 3];
    float v0 = cval[e], v1 = cval[e + 1], v2 = cval[e + 2], v3 = cval[e + 3];
    const unsigned* r0 = X8t + (size_t)m0 * CHUNKS;
    const unsigned* r1 = X8t + (size_t)m1 * CHUNKS;
    const unsigned* r2 = X8t + (size_t)m2 * CHUNKS;
    const unsigned* r3 = X8t + (size_t)m3 * CHUNKS;
    unsigned w0 = r0[c], w1 = r1[c], w2 = r2[c], w3 = r3[c];
    if (extra) {
      unsigned y0 = r0[c2], y1 = r1[c2], y2 = r2[c2], y3 = r3[c2];
      f32x2 a0 = __builtin_amdgcn_cvt_pk_f32_fp8((int)y0, false);
      f32x2 b0 = __builtin_amdgcn_cvt_pk_f32_fp8((int)y0, true);
      f32x2 a1 = __builtin_amdgcn_cvt_pk_f32_fp8((int)y1, false);
      f32x2 b1 = __builtin_amdgcn_cvt_pk_f32_fp8((int)y1, true);
      f32x2 a2 = __builtin_amdgcn_cvt_pk_f32_fp8((int)y2, false);
      f32x2 b2 = __builtin_amdgcn_cvt_pk_f32_fp8((int)y2, true);
      f32x2 a3 = __builtin_amdgcn_cvt_pk_f32_fp8((int)y3, false);
      f32x2 b3 = __builtin_amdgcn_cvt_pk_f32_fp8((int)y3, true);
      ge[0] += v0 * a0[0] + v1 * a1[0] + v2 * a2[0] + v3 * a3[0];
      ge[1] += v0 * a0[1] + v1 * a1[1] + v2 * a2[1] + v3 * a3[1];
      ge[2] += v0 * b0[0] + v1 * b1[0] + v2 * b2[0] + v3 * b3[0];
      ge[3] += v0 * b0[1] + v1 * b1[1] + v2 * b2[1] + v3 * b3[1];
    }
    f32x2 l0 = __builtin_amdgcn_cvt_pk_f32_fp8((int)w0, false);
    f32x2 h0 = __builtin_amdgcn_cvt_pk_f32_fp8((int)w0, true);
    f32x2 l1 = __builtin_amdgcn_cvt_pk_f32_fp8((int)w1, false);
    f32x2 h1 = __builtin_amdgcn_cvt_pk_f32_fp8((int)w1, true);
    f32x2 l2 = __builtin_amdgcn_cvt_pk_f32_fp8((int)w2, false);
    f32x2 h2 = __builtin_amdgcn_cvt_pk_f32_fp8((int)w2, true);
    f32x2 l3 = __builtin_amdgcn_cvt_pk_f32_fp8((int)w3, false);
    f32x2 h3 = __builtin_amdgcn_cvt_pk_f32_fp8((int)w3, true);
    g[0] += v0 * l0[0] + v1 * l1[0] + v2 * l2[0] + v3 * l3[0];
    g[1] += v0 * l0[1] + v1 * l1[1] + v2 * l2[1] + v3 * l3[1];
    g[2] += v0 * h0[0] + v1 * h1[0] + v2 * h2[0] + v3 * h3[0];
    g[3] += v0 * h0[1] + v1 * h1[1] + v2 * h2[1] + v3 * h3[1];
  }
  for (; e < e1; ++e) {
    int m0 = cidx[e];
    float v0 = cval[e];
    const unsigned* r0 = X8t + (size_t)m0 * CHUNKS;
    unsigned w0 = r0[c];
    if (extra) {
      unsigned y0 = r0[c2];
      f32x2 a0 = __builtin_amdgcn_cvt_pk_f32_fp8((int)y0, false);
      f32x2 b0 = __builtin_amdgcn_cvt_pk_f32_fp8((int)y0, true);
      ge[0] += v0 * a0[0]; ge[1] += v0 * a0[1]; ge[2] += v0 * b0[0]; ge[3] += v0 * b0[1];
    }
    f32x2 l0 = __builtin_amdgcn_cvt_pk_f32_fp8((int)w0, false);
    f32x2 h0 = __builtin_amdgcn_cvt_pk_f32_fp8((int)w0, true);
    g[0] += v0 * l0[0]; g[1] += v0 * l0[1]; g[2] += v0 * h0[0]; g[3] += v0 * h0[1];
  }
  int b = c / FQ, fq = c - (c / FQ) * FQ;
  u16x8 wv;
#pragma unroll
  for (int j = 0; j < 4; ++j) { wv[2 * j] = own[j]; wv[2 * j + 1] = f2bf(g[j]); }
  *reinterpret_cast<u16x8*>(Y + (b * LDSC + fq) * 8) = wv;
  if (extra) {
    u16x8 wv2;
#pragma unroll
    for (int j = 0; j < 4; ++j) { wv2[2 * j] = own2[j]; wv2[2 * j + 1] = f2bf(ge[j]); }
    *reinterpret_cast<u16x8*>(Y + (15 * LDSC + (t + 1)) * 8) = wv2;   // c2: b=15, fq=t+1
  }
  __syncthreads();
}

// A-frag: lane (ml,s) kt reads 16B = (x0[f0],x1[f0],...,x0[f0+3],x1[f0+3]), f0=kt*16+s*4
__device__ __forceinline__ void build_afrag(const unsigned short* Y, int ml, int s, bf16x8* af) {
#pragma unroll
  for (int kt = 0; kt < KTILES; ++kt)
    af[kt] = *reinterpret_cast<const bf16x8*>(Y + (ml * LDSC + kt * 4 + s) * 8);
}

// ------- gates: gconv1 (MFMA) + sigmoid; r*h -> X8c (fp8, LDS-staged), {u,u*h} -> upk -------
__global__ __launch_bounds__(256) void gates_kernel(
    const unsigned short* __restrict__ X0, const unsigned* __restrict__ X8,
    const short* __restrict__ W1p, const float* __restrict__ B1,
    const int* __restrict__ rowptr, const int* __restrict__ cidx, const float* __restrict__ cval,
    unsigned* __restrict__ X8c, unsigned* __restrict__ upk) {
  __shared__ __align__(16) unsigned short Y[16 * LDSC * 8];
  __shared__ __align__(16) unsigned X8s[CHUNKS];
  int n = blockIdx.x, t = threadIdx.x;
  gather_node<true>(X0, X8, rowptr, cidx, cval, n, t, Y);

  int lane = t & 63, w = t >> 6, ml = lane & 15, s = lane >> 4;
  bf16x8 af[KTILES];
  build_afrag(Y, ml, s, af);

  // init fp8 row staging: inputs at fq==0 bytes {0,1}, zeros elsewhere
  {
    int b = t / FQ, fq = t - (t / FQ) * FQ;
    unsigned val = 0;
    if (fq == 0) {
      float i0 = bf2f(Y[(b * LDSC) * 8 + 0]);
      float i1 = bf2f(Y[(b * LDSC) * 8 + 2]);
      val = pk4fp8(i0, i1, 0.f, 0.f);
    }
    X8s[t] = val;
    if (t < CHUNKS - 256) X8s[256 + t] = 0u;   // fq = t+1 != 0
  }
  __syncthreads();

  const bf16x8* Wp = (const bf16x8*)W1p;
#pragma unroll
  for (int q = 0; q < 2; ++q) {
    int nt = w * 2 + q;
    f32x4 acc = {0.f, 0.f, 0.f, 0.f};
#pragma unroll
    for (int kt = 0; kt < KTILES; ++kt)
      acc = __builtin_amdgcn_mfma_f32_16x16x32_bf16(af[kt], Wp[(nt * KTILES + kt) * 64 + lane],
                                                    acc, 0, 0, 0);
    int o = nt * 16 + ml;           // output col; rows = batch s*4+r
    float bias = B1[o];
    int f = (o < UNITS ? o : o - UNITS) + IND, fqi = f >> 2, fr = f & 3;
    if (o < UNITS) {
#pragma unroll
      for (int r = 0; r < 4; ++r) {
        int b = s * 4 + r;
        float h = bf2f(Y[(b * LDSC + fqi) * 8 + 2 * fr]);   // h (bf16) from staged own-row
        float sg = 1.f / (1.f + __expf(-(acc[r] + bias)));
        ((unsigned char*)X8s)[(b * FQ + fqi) * 4 + fr] = f2fp8(sg * h);
      }
    } else {
      int ou = o - UNITS;
#pragma unroll
      for (int r = 0; r < 4; ++r) {
        int b = s * 4 + r;
        float h = bf2f(Y[(b * LDSC + fqi) * 8 + 2 * fr]);
        float u = 1.f / (1.f + __expf(-(acc[r] + bias)));
        unsigned pk = (unsigned)f2bf(u) | ((unsigned)f2bf(u * h) << 16);
        upk[(size_t)b * HXS + n * UNITS + ou] = pk;
      }
    }
  }
  __syncthreads();
  // coalesced fp8 row store
  X8c[(size_t)n * CHUNKS + t] = X8s[t];
  if (t < CHUNKS - 256) X8c[(size_t)n * CHUNKS + 256 + t] = X8s[256 + t];
}

// ------- candidate: gconv2 (MFMA) + tanh + GRU combine (out = uh + (1-u)*c) -------
__global__ __launch_bounds__(256) void cand_kernel(
    const unsigned* __restrict__ X8c, const short* __restrict__ W2p,
    const float* __restrict__ B2,
    const int* __restrict__ rowptr, const int* __restrict__ cidx, const float* __restrict__ cval,
    const unsigned* __restrict__ upk, float* __restrict__ out) {
  __shared__ __align__(16) unsigned short Y[16 * LDSC * 8];
  int n = blockIdx.x, t = threadIdx.x;
  gather_node<false>(nullptr, X8c, rowptr, cidx, cval, n, t, Y);

  int lane = t & 63, w = t >> 6, ml = lane & 15, s = lane >> 4;
  bf16x8 af[KTILES];
  build_afrag(Y, ml, s, af);

  const bf16x8* Wp = (const bf16x8*)W2p;
  f32x4 acc = {0.f, 0.f, 0.f, 0.f};
#pragma unroll
  for (int kt = 0; kt < KTILES; ++kt)
    acc = __builtin_amdgcn_mfma_f32_16x16x32_bf16(af[kt], Wp[(w * KTILES + kt) * 64 + lane],
                                                  acc, 0, 0, 0);
  int o = w * 16 + ml;
  float bias = B2[o];
#pragma unroll
  for (int r = 0; r < 4; ++r) {
    int b = s * 4 + r;
    size_t idx = (size_t)b * HXS + n * UNITS + o;
    float x = acc[r] + bias;
    float c = 1.f - 2.f / (__expf(2.f * x) + 1.f);   // tanh
    unsigned pk = upk[idx];
    float u = bf2f((unsigned short)(pk & 0xffffu));
    float uh = bf2f((unsigned short)(pk >> 16));
    out[idx] = uh + (1.f - u) * c;
  }
}

extern "C" void kernel_launch(void* const* d_in, const int* in_sizes, int n_in,
                              void* d_out, int out_size, void* d_ws, size_t ws_size,
                              hipStream_t stream) {
  const float* inputs = (const float*)d_in[0];
  const float* hx     = (const float*)d_in[1];
  const float* eval   = (const float*)d_in[2];
  const float* w1mu   = (const float*)d_in[3];
  const float* w1ls   = (const float*)d_in[4];
  const float* b1mu   = (const float*)d_in[5];
  const float* b1ls   = (const float*)d_in[6];
  const float* w2mu   = (const float*)d_in[7];
  const float* w2ls   = (const float*)d_in[8];
  const float* b2mu   = (const float*)d_in[9];
  const float* b2ls   = (const float*)d_in[10];
  const float* ew1    = (const float*)d_in[11];
  const float* eb1    = (const float*)d_in[12];
  const float* ew2    = (const float*)d_in[13];
  const float* eb2    = (const float*)d_in[14];
  const int* erow     = (const int*)d_in[15];
  const int* ecol     = (const int*)d_in[16];
  float* out = (float*)d_out;

  char* p = (char*)d_ws;
  short* W1p = (short*)p;                   p += 20480 * 2;
  short* W2p = (short*)p;                   p += 10240 * 2;
  float* B1  = (float*)p;                   p += 128 * 4;
  float* B2  = (float*)p;                   p += 64 * 4;
  unsigned short* X0 = (unsigned short*)p;  p += (size_t)N_NODES * RU * 2;
  unsigned* X8  = (unsigned*)p;             p += (size_t)N_NODES * CHUNKS * 4;
  unsigned* X8c = (unsigned*)p;             p += (size_t)N_NODES * CHUNKS * 4;
  unsigned* upk = (unsigned*)p;             p += (size_t)BATCH * HXS * 4;
  int* cnt    = (int*)p;                    p += 10016 * 4;
  int* rowptr = (int*)p;                    p += 10016 * 4;
  int* cursor = (int*)p;                    p += 10016 * 4;
  int* cidx   = (int*)p;                    p += NEDGE * 4;
  float* cval = (float*)p;                  p += NEDGE * 4;

  pack_kernel<<<55, 256, 0, stream>>>(w1mu, w1ls, ew1, b1mu, b1ls, eb1,
                                      w2mu, w2ls, ew2, b2mu, b2ls, eb2,
                                      W1p, W2p, B1, B2, cnt);
  build_x0_kernel<<<(N_NODES * CHUNKS + 255) / 256, 256, 0, stream>>>(inputs, hx, X0, X8,
                                                                      erow, cnt);
  scan_kernel<<<1, 1024, 0, stream>>>(cnt, rowptr, cursor);
  fill_kernel<<<(NEDGE + 255) / 256, 256, 0, stream>>>(erow, ecol, eval, cursor, cidx, cval);
  gates_kernel<<<N_NODES, 256, 0, stream>>>(X0, X8, W1p, B1, rowptr, cidx, cval, X8c, upk);
  cand_kernel<<<N_NODES, 256, 0, stream>>>(X8c, W2p, B2, rowptr, cidx, cval, upk, out);
}

// Round 7
// 112.667 us; speedup vs baseline: 2.8860x; 1.0072x over previous
//
#include <hip/hip_runtime.h>
#include <cmath>

#define N_NODES 10000
#define UNITS   64
#define IND     2
#define BATCH   16
#define NEDGE   80000
#define FDIM    66            // IND + UNITS
#define OG      128           // 2*UNITS
#define OC      64            // UNITS
#define HXS     (N_NODES*UNITS)
#define INS     (N_NODES*IND)
#define KTILES  5             // ceil(132/32)
#define FQ      17            // f-quads per row (F padded 66->68)
#define CHUNKS  272           // 16*17 quads per row
#define RU      1088          // u16 per bf16 row
#define LDSC    21            // padded fq stride in LDS
#define MAXE    128           // LDS-staged edge cap (deg fallback beyond)

typedef __attribute__((ext_vector_type(8))) short bf16x8;
typedef __attribute__((ext_vector_type(4))) float f32x4;
typedef __attribute__((ext_vector_type(2))) float f32x2;
typedef __attribute__((ext_vector_type(4))) unsigned short u16x4;
typedef unsigned long long u64;

__device__ __forceinline__ unsigned short f2bf(float x) {
  union { float f; unsigned u; } v; v.f = x;
  unsigned r = v.u + 0x7fffu + ((v.u >> 16) & 1u);
  return (unsigned short)(r >> 16);
}
__device__ __forceinline__ float bf2f(unsigned short u) {
  union { unsigned u; float f; } v; v.u = ((unsigned)u) << 16; return v.f;
}
__device__ __forceinline__ unsigned cvt2bf(float a, float b) {   // lo=bf16(a), hi=bf16(b)
  unsigned r; asm("v_cvt_pk_bf16_f32 %0, %1, %2" : "=v"(r) : "v"(a), "v"(b)); return r;
}
__device__ __forceinline__ unsigned pk4fp8(float a, float b, float c, float d) {
  int v = __builtin_amdgcn_cvt_pk_fp8_f32(a, b, 0, false);
  v = __builtin_amdgcn_cvt_pk_fp8_f32(c, d, v, true);
  return (unsigned)v;
}
__device__ __forceinline__ unsigned char f2fp8(float a) {
  return (unsigned char)(__builtin_amdgcn_cvt_pk_fp8_f32(a, 0.f, 0, false) & 0xff);
}

// ------- pack W (fused reparam) into MFMA B-frag lane order + biases + zero cnt -------
// New k-order: k = kt*32 + s*8 + j maps to feature f = kt*16 + s*4 + (j&3),
// matrix src = j>>2 (0=x0, 1=x1)  ->  original W row = 2*f + src.
__global__ void pack_kernel(const float* __restrict__ w1mu, const float* __restrict__ w1ls,
                            const float* __restrict__ ew1,
                            const float* __restrict__ b1mu, const float* __restrict__ b1ls,
                            const float* __restrict__ eb1,
                            const float* __restrict__ w2mu, const float* __restrict__ w2ls,
                            const float* __restrict__ ew2,
                            const float* __restrict__ b2mu, const float* __restrict__ b2ls,
                            const float* __restrict__ eb2,
                            short* __restrict__ W1p, short* __restrict__ W2p,
                            float* __restrict__ B1, float* __restrict__ B2,
                            int* __restrict__ cnt) {
  int i = blockIdx.x * 256 + threadIdx.x;
  if (i < 2560) {
    int l = i & 63, kt = (i >> 6) % KTILES, nt = i / (KTILES * 64);
    int o = nt * 16 + (l & 15);
    int s = l >> 4;
    bf16x8 fr;
#pragma unroll
    for (int j = 0; j < 8; ++j) {
      int f = kt * 16 + s * 4 + (j & 3);
      int src = j >> 2;
      float w = 0.f;
      if (f < FDIM) { int idx = (2 * f + src) * OG + o; w = w1mu[idx] + __expf(w1ls[idx]) * ew1[idx]; }
      fr[j] = (short)f2bf(w);
    }
    *((bf16x8*)W1p + i) = fr;
  } else if (i < 3840) {
    int i2 = i - 2560;
    int l = i2 & 63, kt = (i2 >> 6) % KTILES, nt = i2 / (KTILES * 64);
    int o = nt * 16 + (l & 15);
    int s = l >> 4;
    bf16x8 fr;
#pragma unroll
    for (int j = 0; j < 8; ++j) {
      int f = kt * 16 + s * 4 + (j & 3);
      int src = j >> 2;
      float w = 0.f;
      if (f < FDIM) { int idx = (2 * f + src) * OC + o; w = w2mu[idx] + __expf(w2ls[idx]) * ew2[idx]; }
      fr[j] = (short)f2bf(w);
    }
    *((bf16x8*)W2p + i2) = fr;
  } else if (i < 3968) {
    int j = i - 3840; B1[j] = b1mu[j] + __expf(b1ls[j]) * eb1[j];
  } else if (i < 4032) {
    int j = i - 3968; B2[j] = b2mu[j] + __expf(b2ls[j]) * eb2[j];
  } else if (i < 4032 + 10016) {
    cnt[i - 4032] = 0;
  }
}

// ------- build X0 (bf16) + X8 (fp8 shadow) [N][b:16][fq:17][4] + fused edge count -------
__global__ void build_x0_kernel(const float* __restrict__ inputs, const float* __restrict__ hx,
                                unsigned short* __restrict__ X0, unsigned* __restrict__ X8,
                                const int* __restrict__ erow, int* __restrict__ cnt) {
  int i = blockIdx.x * 256 + threadIdx.x;
  if (i < NEDGE) atomicAdd(&cnt[erow[i]], 1);
  if (i >= N_NODES * CHUNKS) return;
  int n = i / CHUNKS;
  int c = i - n * CHUNKS;
  int b = c / FQ;
  int fq = c - b * FQ;
  float v0, v1, v2, v3;
  if (fq == 0) {
    const float* ip = inputs + (size_t)b * INS + n * IND;
    const float* hp = hx + (size_t)b * HXS + n * UNITS;
    v0 = ip[0]; v1 = ip[1]; v2 = hp[0]; v3 = hp[1];
  } else if (fq < 16) {
    const float* hp = hx + (size_t)b * HXS + n * UNITS + fq * 4 - 2;
    v0 = hp[0]; v1 = hp[1]; v2 = hp[2]; v3 = hp[3];
  } else {
    const float* hp = hx + (size_t)b * HXS + n * UNITS + 62;
    v0 = hp[0]; v1 = hp[1]; v2 = 0.f; v3 = 0.f;
  }
  u16x4 o4;
  o4[0] = f2bf(v0); o4[1] = f2bf(v1); o4[2] = f2bf(v2); o4[3] = f2bf(v3);
  *reinterpret_cast<u16x4*>(X0 + (size_t)i * 4) = o4;
  X8[i] = pk4fp8(v0, v1, v2, v3);
}

// ------- fast scan -------
__global__ void scan_kernel(const int* __restrict__ cnt, int* __restrict__ rowptr,
                            int* __restrict__ cursor) {
  int t = threadIdx.x;
  int base = t * 10;
  int v[10]; int sum = 0;
#pragma unroll
  for (int j = 0; j < 10; ++j) {
    int idx = base + j;
    int x = (idx < N_NODES) ? cnt[idx] : 0;
    v[j] = sum; sum += x;
  }
  int inc = sum;
  int lane = t & 63, wid = t >> 6;
#pragma unroll
  for (int d = 1; d < 64; d <<= 1) {
    int o = __shfl_up(inc, d, 64);
    if (lane >= d) inc += o;
  }
  __shared__ int wsum[16];
  if (lane == 63) wsum[wid] = inc;
  __syncthreads();
  if (t == 0) {
    int a = 0;
#pragma unroll
    for (int k = 0; k < 16; ++k) { int x = wsum[k]; wsum[k] = a; a += x; }
  }
  __syncthreads();
  int off = wsum[wid] + (inc - sum);
#pragma unroll
  for (int j = 0; j < 10; ++j) {
    int idx = base + j;
    if (idx < N_NODES) { int val = off + v[j]; rowptr[idx] = val; cursor[idx] = val; }
    else if (idx == N_NODES) rowptr[N_NODES] = off + v[j];
  }
}

// ------- fill: packed {col*CHUNKS, val} per edge -------
__global__ void fill_kernel(const int* __restrict__ erow, const int* __restrict__ ecol,
                            const float* __restrict__ eval, int* __restrict__ cursor,
                            u64* __restrict__ epk) {
  int i = blockIdx.x * 256 + threadIdx.x;
  if (i >= NEDGE) return;
  int r = erow[i];
  int p = atomicAdd(&cursor[r], 1);
  epk[p] = (u64)(unsigned)(ecol[i] * CHUNKS) | ((u64)__float_as_uint(eval[i]) << 32);
}

// ------- gather: own row (bf16 or fp8) + fp8 CSR gather -> LDS Y[b][fq']{x0q,x1q} -------
template<bool OWNBF>
__device__ __forceinline__ void gather_node(const unsigned short* __restrict__ XownB,
                                            const unsigned* __restrict__ X8t,
                                            const int* __restrict__ rowptr,
                                            const u64* __restrict__ epk,
                                            int n, int t, unsigned short* Y,
                                            u64* __restrict__ eds) {
  if (t < 48) {                       // zero LDS pads fq' 17..19
    int b = t / 3, fqp = 17 + (t - (t / 3) * 3);
    *reinterpret_cast<uint4*>(Y + (b * LDSC + fqp) * 8) = make_uint4(0u, 0u, 0u, 0u);
  }
  int e0 = rowptr[n], deg = rowptr[n + 1] - e0;
  if (t < deg && t < MAXE) eds[t] = epk[e0 + t];

  const int c = t, c2 = 256 + t;
  const bool extra = t < (CHUNKS - 256);
  unsigned ow0, ow1, ow0e = 0, ow1e = 0;
  if (OWNBF) {
    const unsigned* xrow = reinterpret_cast<const unsigned*>(XownB + (size_t)n * RU);
    ow0 = xrow[c * 2]; ow1 = xrow[c * 2 + 1];
    if (extra) { ow0e = xrow[c2 * 2]; ow1e = xrow[c2 * 2 + 1]; }
  } else {
    const unsigned* xrow = X8t + (size_t)n * CHUNKS;
    unsigned wo = xrow[c];
    f32x2 lo = __builtin_amdgcn_cvt_pk_f32_fp8((int)wo, false);
    f32x2 hi = __builtin_amdgcn_cvt_pk_f32_fp8((int)wo, true);
    ow0 = cvt2bf(lo[0], lo[1]); ow1 = cvt2bf(hi[0], hi[1]);
    if (extra) {
      unsigned wo2 = xrow[c2];
      f32x2 lo2 = __builtin_amdgcn_cvt_pk_f32_fp8((int)wo2, false);
      f32x2 hi2 = __builtin_amdgcn_cvt_pk_f32_fp8((int)wo2, true);
      ow0e = cvt2bf(lo2[0], lo2[1]); ow1e = cvt2bf(hi2[0], hi2[1]);
    }
  }
  __syncthreads();   // eds visible

  f32x2 g01 = {0.f, 0.f}, g23 = {0.f, 0.f}, ge01 = {0.f, 0.f}, ge23 = {0.f, 0.f};
  const unsigned* bc = X8t + c;
  const unsigned* bc2 = X8t + c2;
  int nd = deg < MAXE ? deg : MAXE;
  int e = 0;
  for (; e + 4 <= nd; e += 4) {
    u64 p0 = eds[e], p1 = eds[e + 1], p2 = eds[e + 2], p3 = eds[e + 3];
    unsigned o0 = (unsigned)p0, o1 = (unsigned)p1, o2 = (unsigned)p2, o3 = (unsigned)p3;
    float v0 = __uint_as_float((unsigned)(p0 >> 32));
    float v1 = __uint_as_float((unsigned)(p1 >> 32));
    float v2 = __uint_as_float((unsigned)(p2 >> 32));
    float v3 = __uint_as_float((unsigned)(p3 >> 32));
    unsigned w0 = bc[o0], w1 = bc[o1], w2 = bc[o2], w3 = bc[o3];
    f32x2 vv0 = {v0, v0}, vv1 = {v1, v1}, vv2 = {v2, v2}, vv3 = {v3, v3};
    if (extra) {
      unsigned y0 = bc2[o0], y1 = bc2[o1], y2 = bc2[o2], y3 = bc2[o3];
      ge01 += vv0 * __builtin_amdgcn_cvt_pk_f32_fp8((int)y0, false);
      ge23 += vv0 * __builtin_amdgcn_cvt_pk_f32_fp8((int)y0, true);
      ge01 += vv1 * __builtin_amdgcn_cvt_pk_f32_fp8((int)y1, false);
      ge23 += vv1 * __builtin_amdgcn_cvt_pk_f32_fp8((int)y1, true);
      ge01 += vv2 * __builtin_amdgcn_cvt_pk_f32_fp8((int)y2, false);
      ge23 += vv2 * __builtin_amdgcn_cvt_pk_f32_fp8((int)y2, true);
      ge01 += vv3 * __builtin_amdgcn_cvt_pk_f32_fp8((int)y3, false);
      ge23 += vv3 * __builtin_amdgcn_cvt_pk_f32_fp8((int)y3, true);
    }
    g01 += vv0 * __builtin_amdgcn_cvt_pk_f32_fp8((int)w0, false);
    g23 += vv0 * __builtin_amdgcn_cvt_pk_f32_fp8((int)w0, true);
    g01 += vv1 * __builtin_amdgcn_cvt_pk_f32_fp8((int)w1, false);
    g23 += vv1 * __builtin_amdgcn_cvt_pk_f32_fp8((int)w1, true);
    g01 += vv2 * __builtin_amdgcn_cvt_pk_f32_fp8((int)w2, false);
    g23 += vv2 * __builtin_amdgcn_cvt_pk_f32_fp8((int)w2, true);
    g01 += vv3 * __builtin_amdgcn_cvt_pk_f32_fp8((int)w3, false);
    g23 += vv3 * __builtin_amdgcn_cvt_pk_f32_fp8((int)w3, true);
  }
  for (; e < nd; ++e) {
    u64 p0 = eds[e];
    unsigned o0 = (unsigned)p0;
    float v0 = __uint_as_float((unsigned)(p0 >> 32));
    f32x2 vv0 = {v0, v0};
    unsigned w0 = bc[o0];
    if (extra) {
      unsigned y0 = bc2[o0];
      ge01 += vv0 * __builtin_amdgcn_cvt_pk_f32_fp8((int)y0, false);
      ge23 += vv0 * __builtin_amdgcn_cvt_pk_f32_fp8((int)y0, true);
    }
    g01 += vv0 * __builtin_amdgcn_cvt_pk_f32_fp8((int)w0, false);
    g23 += vv0 * __builtin_amdgcn_cvt_pk_f32_fp8((int)w0, true);
  }
  for (int ee = MAXE; ee < deg; ++ee) {      // safety fallback (deg > MAXE)
    u64 p0 = epk[e0 + ee];
    unsigned o0 = (unsigned)p0;
    float v0 = __uint_as_float((unsigned)(p0 >> 32));
    f32x2 vv0 = {v0, v0};
    unsigned w0 = bc[o0];
    if (extra) {
      unsigned y0 = bc2[o0];
      ge01 += vv0 * __builtin_amdgcn_cvt_pk_f32_fp8((int)y0, false);
      ge23 += vv0 * __builtin_amdgcn_cvt_pk_f32_fp8((int)y0, true);
    }
    g01 += vv0 * __builtin_amdgcn_cvt_pk_f32_fp8((int)w0, false);
    g23 += vv0 * __builtin_amdgcn_cvt_pk_f32_fp8((int)w0, true);
  }

  int b = c / FQ, fq = c - (c / FQ) * FQ;
  *reinterpret_cast<uint4*>(Y + (b * LDSC + fq) * 8) =
      make_uint4(ow0, ow1, cvt2bf(g01[0], g01[1]), cvt2bf(g23[0], g23[1]));
  if (extra) {
    *reinterpret_cast<uint4*>(Y + (15 * LDSC + (t + 1)) * 8) =
        make_uint4(ow0e, ow1e, cvt2bf(ge01[0], ge01[1]), cvt2bf(ge23[0], ge23[1]));
  }
  __syncthreads();
}

// A-frag: lane (ml,s) kt reads 16B = (x0[f0..f0+3], x1[f0..f0+3]), f0 = kt*16+s*4
__device__ __forceinline__ void build_afrag(const unsigned short* Y, int ml, int s, bf16x8* af) {
#pragma unroll
  for (int kt = 0; kt < KTILES; ++kt)
    af[kt] = *reinterpret_cast<const bf16x8*>(Y + (ml * LDSC + kt * 4 + s) * 8);
}

// ------- gates: gconv1 (MFMA) + sigmoid; r*h -> X8c (fp8, LDS-staged), {u,u*h} -> upk -------
__global__ __launch_bounds__(256) void gates_kernel(
    const unsigned short* __restrict__ X0, const unsigned* __restrict__ X8,
    const short* __restrict__ W1p, const float* __restrict__ B1,
    const int* __restrict__ rowptr, const u64* __restrict__ epk,
    unsigned* __restrict__ X8c, unsigned* __restrict__ upk) {
  __shared__ __align__(16) unsigned short Y[16 * LDSC * 8];
  __shared__ __align__(16) unsigned X8s[CHUNKS];
  __shared__ __align__(16) u64 eds[MAXE];
  int n = blockIdx.x, t = threadIdx.x;
  gather_node<true>(X0, X8, rowptr, epk, n, t, Y, eds);

  int lane = t & 63, w = t >> 6, ml = lane & 15, s = lane >> 4;
  bf16x8 af[KTILES];
  build_afrag(Y, ml, s, af);

  // init fp8 row staging: inputs at fq==0 bytes {0,1}, zeros elsewhere
  {
    int fq = t - (t / FQ) * FQ;
    unsigned val = 0;
    if (fq == 0) {
      int b = t / FQ;
      float i0 = bf2f(Y[(b * LDSC) * 8 + 0]);
      float i1 = bf2f(Y[(b * LDSC) * 8 + 1]);
      val = pk4fp8(i0, i1, 0.f, 0.f);
    }
    X8s[t] = val;
    if (t < CHUNKS - 256) X8s[256 + t] = 0u;   // fq = t+1 != 0
  }
  __syncthreads();

  const bf16x8* Wp = (const bf16x8*)W1p;
#pragma unroll
  for (int q = 0; q < 2; ++q) {
    int nt = w * 2 + q;
    f32x4 acc = {0.f, 0.f, 0.f, 0.f};
#pragma unroll
    for (int kt = 0; kt < KTILES; ++kt)
      acc = __builtin_amdgcn_mfma_f32_16x16x32_bf16(af[kt], Wp[(nt * KTILES + kt) * 64 + lane],
                                                    acc, 0, 0, 0);
    int o = nt * 16 + ml;           // output col; rows = batch s*4+r
    float bias = B1[o];
    int f = (o < UNITS ? o : o - UNITS) + IND, fqi = f >> 2, fr = f & 3;
    if (o < UNITS) {
#pragma unroll
      for (int r = 0; r < 4; ++r) {
        int b = s * 4 + r;
        float h = bf2f(Y[(b * LDSC + fqi) * 8 + fr]);   // h (bf16) from staged own-row x0 quad
        float sg = 1.f / (1.f + __expf(-(acc[r] + bias)));
        ((unsigned char*)X8s)[(b * FQ + fqi) * 4 + fr] = f2fp8(sg * h);
      }
    } else {
      int ou = o - UNITS;
#pragma unroll
      for (int r = 0; r < 4; ++r) {
        int b = s * 4 + r;
        float h = bf2f(Y[(b * LDSC + fqi) * 8 + fr]);
        float u = 1.f / (1.f + __expf(-(acc[r] + bias)));
        upk[(size_t)b * HXS + n * UNITS + ou] = cvt2bf(u, u * h);
      }
    }
  }
  __syncthreads();
  // coalesced fp8 row store
  X8c[(size_t)n * CHUNKS + t] = X8s[t];
  if (t < CHUNKS - 256) X8c[(size_t)n * CHUNKS + 256 + t] = X8s[256 + t];
}

// ------- candidate: gconv2 (MFMA) + tanh + GRU combine (out = uh + (1-u)*c) -------
__global__ __launch_bounds__(256) void cand_kernel(
    const unsigned* __restrict__ X8c, const short* __restrict__ W2p,
    const float* __restrict__ B2,
    const int* __restrict__ rowptr, const u64* __restrict__ epk,
    const unsigned* __restrict__ upk, float* __restrict__ out) {
  __shared__ __align__(16) unsigned short Y[16 * LDSC * 8];
  __shared__ __align__(16) u64 eds[MAXE];
  int n = blockIdx.x, t = threadIdx.x;
  gather_node<false>(nullptr, X8c, rowptr, epk, n, t, Y, eds);

  int lane = t & 63, w = t >> 6, ml = lane & 15, s = lane >> 4;
  bf16x8 af[KTILES];
  build_afrag(Y, ml, s, af);

  const bf16x8* Wp = (const bf16x8*)W2p;
  f32x4 acc = {0.f, 0.f, 0.f, 0.f};
#pragma unroll
  for (int kt = 0; kt < KTILES; ++kt)
    acc = __builtin_amdgcn_mfma_f32_16x16x32_bf16(af[kt], Wp[(w * KTILES + kt) * 64 + lane],
                                                  acc, 0, 0, 0);
  int o = w * 16 + ml;
  float bias = B2[o];
#pragma unroll
  for (int r = 0; r < 4; ++r) {
    int b = s * 4 + r;
    size_t idx = (size_t)b * HXS + n * UNITS + o;
    float x = acc[r] + bias;
    float c = 1.f - 2.f / (__expf(2.f * x) + 1.f);   // tanh
    unsigned pk = upk[idx];
    float u = bf2f((unsigned short)(pk & 0xffffu));
    float uh = bf2f((unsigned short)(pk >> 16));
    out[idx] = uh + (1.f - u) * c;
  }
}

extern "C" void kernel_launch(void* const* d_in, const int* in_sizes, int n_in,
                              void* d_out, int out_size, void* d_ws, size_t ws_size,
                              hipStream_t stream) {
  const float* inputs = (const float*)d_in[0];
  const float* hx     = (const float*)d_in[1];
  const float* eval   = (const float*)d_in[2];
  const float* w1mu   = (const float*)d_in[3];
  const float* w1ls   = (const float*)d_in[4];
  const float* b1mu   = (const float*)d_in[5];
  const float* b1ls   = (const float*)d_in[6];
  const float* w2mu   = (const float*)d_in[7];
  const float* w2ls   = (const float*)d_in[8];
  const float* b2mu   = (const float*)d_in[9];
  const float* b2ls   = (const float*)d_in[10];
  const float* ew1    = (const float*)d_in[11];
  const float* eb1    = (const float*)d_in[12];
  const float* ew2    = (const float*)d_in[13];
  const float* eb2    = (const float*)d_in[14];
  const int* erow     = (const int*)d_in[15];
  const int* ecol     = (const int*)d_in[16];
  float* out = (float*)d_out;

  char* p = (char*)d_ws;
  short* W1p = (short*)p;                   p += 20480 * 2;
  short* W2p = (short*)p;                   p += 10240 * 2;
  float* B1  = (float*)p;                   p += 128 * 4;
  float* B2  = (float*)p;                   p += 64 * 4;
  unsigned short* X0 = (unsigned short*)p;  p += (size_t)N_NODES * RU * 2;
  unsigned* X8  = (unsigned*)p;             p += (size_t)N_NODES * CHUNKS * 4;
  unsigned* X8c = (unsigned*)p;             p += (size_t)N_NODES * CHUNKS * 4;
  unsigned* upk = (unsigned*)p;             p += (size_t)BATCH * HXS * 4;
  int* cnt    = (int*)p;                    p += 10016 * 4;
  int* rowptr = (int*)p;                    p += 10016 * 4;
  int* cursor = (int*)p;                    p += 10016 * 4;
  u64* epk    = (u64*)p;                    p += NEDGE * 8;

  pack_kernel<<<55, 256, 0, stream>>>(w1mu, w1ls, ew1, b1mu, b1ls, eb1,
                                      w2mu, w2ls, ew2, b2mu, b2ls, eb2,
                                      W1p, W2p, B1, B2, cnt);
  build_x0_kernel<<<(N_NODES * CHUNKS + 255) / 256, 256, 0, stream>>>(inputs, hx, X0, X8,
                                                                      erow, cnt);
  scan_kernel<<<1, 1024, 0, stream>>>(cnt, rowptr, cursor);
  fill_kernel<<<(NEDGE + 255) / 256, 256, 0, stream>>>(erow, ecol, eval, cursor, epk);
  gates_kernel<<<N_NODES, 256, 0, stream>>>(X0, X8, W1p, B1, rowptr, epk, X8c, upk);
  cand_kernel<<<N_NODES, 256, 0, stream>>>(X8c, W2p, B2, rowptr, epk, upk, out);
}

// Round 8
// 95.233 us; speedup vs baseline: 3.4143x; 1.1831x over previous
//
#include <hip/hip_runtime.h>
#include <cmath>

#define N_NODES 10000
#define UNITS   64
#define IND     2
#define BATCH   16
#define NEDGE   80000
#define FDIM    66            // IND + UNITS
#define OG      128           // 2*UNITS
#define OC      64            // UNITS
#define HXS     (N_NODES*UNITS)
#define INS     (N_NODES*IND)
#define KTILES  5             // ceil(132/32)
#define FQ      17            // f-quads per row (F padded 66->68)
#define CHUNKS  272           // 16*17 quads per row
#define LDSC    21            // padded fq stride in LDS
#define CAP     64            // bucket capacity per node (mean deg 8)

typedef __attribute__((ext_vector_type(8))) short bf16x8;
typedef __attribute__((ext_vector_type(4))) float f32x4;
typedef __attribute__((ext_vector_type(2))) float f32x2;
typedef unsigned long long u64;

__device__ __forceinline__ float bf2f(unsigned short u) {
  union { unsigned u; float f; } v; v.u = ((unsigned)u) << 16; return v.f;
}
__device__ __forceinline__ unsigned short f2bf(float x) {
  union { float f; unsigned u; } v; v.f = x;
  unsigned r = v.u + 0x7fffu + ((v.u >> 16) & 1u);
  return (unsigned short)(r >> 16);
}
__device__ __forceinline__ unsigned cvt2bf(float a, float b) {   // lo=bf16(a), hi=bf16(b)
  unsigned r; asm("v_cvt_pk_bf16_f32 %0, %1, %2" : "=v"(r) : "v"(a), "v"(b)); return r;
}
__device__ __forceinline__ unsigned pk4fp8(float a, float b, float c, float d) {
  int v = __builtin_amdgcn_cvt_pk_fp8_f32(a, b, 0, false);
  v = __builtin_amdgcn_cvt_pk_fp8_f32(c, d, v, true);
  return (unsigned)v;
}
__device__ __forceinline__ unsigned char f2fp8(float a) {
  return (unsigned char)(__builtin_amdgcn_cvt_pk_fp8_f32(a, 0.f, 0, false) & 0xff);
}

// ================= fused prep: pack W | fill buckets | build X8 =================
// k-order for A/B frags: k = kt*32 + s*8 + j -> feature f = kt*16 + s*4 + (j&3),
// src = j>>2 (0=x0, 1=x1) -> original W row = 2*f + src.
__global__ __launch_bounds__(256) void prep_kernel(
    const float* __restrict__ inputs, const float* __restrict__ hx,
    const float* __restrict__ w1mu, const float* __restrict__ w1ls, const float* __restrict__ ew1,
    const float* __restrict__ b1mu, const float* __restrict__ b1ls, const float* __restrict__ eb1,
    const float* __restrict__ w2mu, const float* __restrict__ w2ls, const float* __restrict__ ew2,
    const float* __restrict__ b2mu, const float* __restrict__ b2ls, const float* __restrict__ eb2,
    const int* __restrict__ erow, const int* __restrict__ ecol, const float* __restrict__ eval,
    short* __restrict__ W1p, short* __restrict__ W2p,
    float* __restrict__ B1, float* __restrict__ B2,
    int* __restrict__ cnt, u64* __restrict__ epk, unsigned* __restrict__ X8) {
  int blk = blockIdx.x, t = threadIdx.x;
  if (blk < 16) {                    // ---- pack W (fused reparam) ----
    int i = blk * 256 + t;
    if (i < 2560) {
      int l = i & 63, kt = (i >> 6) % KTILES, nt = i / (KTILES * 64);
      int o = nt * 16 + (l & 15), s = l >> 4;
      bf16x8 fr;
#pragma unroll
      for (int j = 0; j < 8; ++j) {
        int f = kt * 16 + s * 4 + (j & 3);
        int src = j >> 2;
        float w = 0.f;
        if (f < FDIM) { int idx = (2 * f + src) * OG + o; w = w1mu[idx] + __expf(w1ls[idx]) * ew1[idx]; }
        fr[j] = (short)f2bf(w);
      }
      *((bf16x8*)W1p + i) = fr;
    } else if (i < 3840) {
      int i2 = i - 2560;
      int l = i2 & 63, kt = (i2 >> 6) % KTILES, nt = i2 / (KTILES * 64);
      int o = nt * 16 + (l & 15), s = l >> 4;
      bf16x8 fr;
#pragma unroll
      for (int j = 0; j < 8; ++j) {
        int f = kt * 16 + s * 4 + (j & 3);
        int src = j >> 2;
        float w = 0.f;
        if (f < FDIM) { int idx = (2 * f + src) * OC + o; w = w2mu[idx] + __expf(w2ls[idx]) * ew2[idx]; }
        fr[j] = (short)f2bf(w);
      }
      *((bf16x8*)W2p + i2) = fr;
    } else if (i < 3968) {
      int j = i - 3840; B1[j] = b1mu[j] + __expf(b1ls[j]) * eb1[j];
    } else if (i < 4032) {
      int j = i - 3968; B2[j] = b2mu[j] + __expf(b2ls[j]) * eb2[j];
    }
  } else if (blk < 16 + 313) {       // ---- fill buckets ----
    int i = (blk - 16) * 256 + t;
    if (i < NEDGE) {
      int r = erow[i];
      int pos = atomicAdd(&cnt[r], 1);
      if (pos < CAP)
        epk[(size_t)r * CAP + pos] =
            (u64)(unsigned)(ecol[i] * CHUNKS) | ((u64)__float_as_uint(eval[i]) << 32);
    }
  } else {                           // ---- build X8 (fp8 [N][b:16][fq:17][4]) ----
    int i = (blk - 329) * 256 + t;
    if (i >= N_NODES * CHUNKS) return;
    int n = i / CHUNKS;
    int c = i - n * CHUNKS;
    int b = c / FQ;
    int fq = c - b * FQ;
    const float* hp = hx + (size_t)b * HXS + n * UNITS;
    float v0, v1, v2, v3;
    if (fq == 0) {
      const float* ip = inputs + (size_t)b * INS + n * IND;
      v0 = ip[0]; v1 = ip[1]; v2 = hp[0]; v3 = hp[1];
    } else if (fq < 16) {
      f32x2 a = *reinterpret_cast<const f32x2*>(hp + fq * 4 - 2);
      f32x2 d = *reinterpret_cast<const f32x2*>(hp + fq * 4);
      v0 = a[0]; v1 = a[1]; v2 = d[0]; v3 = d[1];
    } else {
      f32x2 a = *reinterpret_cast<const f32x2*>(hp + 62);
      v0 = a[0]; v1 = a[1]; v2 = 0.f; v3 = 0.f;
    }
    X8[i] = pk4fp8(v0, v1, v2, v3);
  }
}

// ========== shared gather: fp8 x1 gather + Y write ({own,x1} interleaved) ==========
__device__ __forceinline__ void gather_write(const unsigned* __restrict__ X8t,
                                             int deg, const u64* __restrict__ ebk,
                                             int t, unsigned ow0, unsigned ow1,
                                             unsigned ow0e, unsigned ow1e,
                                             unsigned short* Y, u64* eds) {
  if (t < 48) {                       // zero LDS pads fq' 17..19
    int b = t / 3, fqp = 17 + (t - (t / 3) * 3);
    *reinterpret_cast<uint4*>(Y + (b * LDSC + fqp) * 8) = make_uint4(0u, 0u, 0u, 0u);
  }
  if (t < deg) eds[t] = ebk[t];
  __syncthreads();   // eds visible

  const int c = t, c2 = 256 + t;
  const bool extra = t < (CHUNKS - 256);
  f32x2 g01 = {0.f, 0.f}, g23 = {0.f, 0.f}, ge01 = {0.f, 0.f}, ge23 = {0.f, 0.f};
  const unsigned* bc = X8t + c;
  const unsigned* bc2 = X8t + c2;
  int e = 0;
  for (; e + 4 <= deg; e += 4) {
    u64 p0 = eds[e], p1 = eds[e + 1], p2 = eds[e + 2], p3 = eds[e + 3];
    unsigned o0 = (unsigned)p0, o1 = (unsigned)p1, o2 = (unsigned)p2, o3 = (unsigned)p3;
    float v0 = __uint_as_float((unsigned)(p0 >> 32));
    float v1 = __uint_as_float((unsigned)(p1 >> 32));
    float v2 = __uint_as_float((unsigned)(p2 >> 32));
    float v3 = __uint_as_float((unsigned)(p3 >> 32));
    unsigned w0 = bc[o0], w1 = bc[o1], w2 = bc[o2], w3 = bc[o3];
    f32x2 vv0 = {v0, v0}, vv1 = {v1, v1}, vv2 = {v2, v2}, vv3 = {v3, v3};
    if (extra) {
      unsigned y0 = bc2[o0], y1 = bc2[o1], y2 = bc2[o2], y3 = bc2[o3];
      ge01 += vv0 * __builtin_amdgcn_cvt_pk_f32_fp8((int)y0, false);
      ge23 += vv0 * __builtin_amdgcn_cvt_pk_f32_fp8((int)y0, true);
      ge01 += vv1 * __builtin_amdgcn_cvt_pk_f32_fp8((int)y1, false);
      ge23 += vv1 * __builtin_amdgcn_cvt_pk_f32_fp8((int)y1, true);
      ge01 += vv2 * __builtin_amdgcn_cvt_pk_f32_fp8((int)y2, false);
      ge23 += vv2 * __builtin_amdgcn_cvt_pk_f32_fp8((int)y2, true);
      ge01 += vv3 * __builtin_amdgcn_cvt_pk_f32_fp8((int)y3, false);
      ge23 += vv3 * __builtin_amdgcn_cvt_pk_f32_fp8((int)y3, true);
    }
    g01 += vv0 * __builtin_amdgcn_cvt_pk_f32_fp8((int)w0, false);
    g23 += vv0 * __builtin_amdgcn_cvt_pk_f32_fp8((int)w0, true);
    g01 += vv1 * __builtin_amdgcn_cvt_pk_f32_fp8((int)w1, false);
    g23 += vv1 * __builtin_amdgcn_cvt_pk_f32_fp8((int)w1, true);
    g01 += vv2 * __builtin_amdgcn_cvt_pk_f32_fp8((int)w2, false);
    g23 += vv2 * __builtin_amdgcn_cvt_pk_f32_fp8((int)w2, true);
    g01 += vv3 * __builtin_amdgcn_cvt_pk_f32_fp8((int)w3, false);
    g23 += vv3 * __builtin_amdgcn_cvt_pk_f32_fp8((int)w3, true);
  }
  for (; e < deg; ++e) {
    u64 p0 = eds[e];
    unsigned o0 = (unsigned)p0;
    float v0 = __uint_as_float((unsigned)(p0 >> 32));
    f32x2 vv0 = {v0, v0};
    unsigned w0 = bc[o0];
    if (extra) {
      unsigned y0 = bc2[o0];
      ge01 += vv0 * __builtin_amdgcn_cvt_pk_f32_fp8((int)y0, false);
      ge23 += vv0 * __builtin_amdgcn_cvt_pk_f32_fp8((int)y0, true);
    }
    g01 += vv0 * __builtin_amdgcn_cvt_pk_f32_fp8((int)w0, false);
    g23 += vv0 * __builtin_amdgcn_cvt_pk_f32_fp8((int)w0, true);
  }

  int b = c / FQ, fq = c - (c / FQ) * FQ;
  *reinterpret_cast<uint4*>(Y + (b * LDSC + fq) * 8) =
      make_uint4(ow0, ow1, cvt2bf(g01[0], g01[1]), cvt2bf(g23[0], g23[1]));
  if (extra) {
    *reinterpret_cast<uint4*>(Y + (15 * LDSC + (t + 1)) * 8) =
        make_uint4(ow0e, ow1e, cvt2bf(ge01[0], ge01[1]), cvt2bf(ge23[0], ge23[1]));
  }
  __syncthreads();
}

// A-frag: lane (ml,s) kt reads 16B = (x0[f0..f0+3], x1[f0..f0+3]), f0 = kt*16+s*4
__device__ __forceinline__ void build_afrag(const unsigned short* Y, int ml, int s, bf16x8* af) {
#pragma unroll
  for (int kt = 0; kt < KTILES; ++kt)
    af[kt] = *reinterpret_cast<const bf16x8*>(Y + (ml * LDSC + kt * 4 + s) * 8);
}

// ------- gates: own row from fp32 hx/inputs; gconv1 (MFMA) + sigmoid;
//         r*h -> X8c (fp8, LDS-staged), {u,u*h} -> upk -------
__global__ __launch_bounds__(256) void gates_kernel(
    const float* __restrict__ inputs, const float* __restrict__ hx,
    const unsigned* __restrict__ X8,
    const short* __restrict__ W1p, const float* __restrict__ B1,
    const int* __restrict__ cnt, const u64* __restrict__ epk,
    unsigned* __restrict__ X8c, unsigned* __restrict__ upk) {
  __shared__ __align__(16) unsigned short Y[16 * LDSC * 8];
  __shared__ __align__(16) unsigned X8s[CHUNKS];
  __shared__ __align__(16) u64 eds[CAP];
  int n = blockIdx.x, t = threadIdx.x;

  // own row straight from fp32 sources
  int b0 = t / FQ, fq0 = t - b0 * FQ;
  const float* hp = hx + (size_t)b0 * HXS + n * UNITS;
  float v0, v1, v2, v3;
  if (fq0 == 0) {
    const float* ip = inputs + (size_t)b0 * INS + n * IND;
    v0 = ip[0]; v1 = ip[1]; v2 = hp[0]; v3 = hp[1];
  } else if (fq0 < 16) {
    f32x2 a = *reinterpret_cast<const f32x2*>(hp + fq0 * 4 - 2);
    f32x2 d = *reinterpret_cast<const f32x2*>(hp + fq0 * 4);
    v0 = a[0]; v1 = a[1]; v2 = d[0]; v3 = d[1];
  } else {
    f32x2 a = *reinterpret_cast<const f32x2*>(hp + 62);
    v0 = a[0]; v1 = a[1]; v2 = 0.f; v3 = 0.f;
  }
  unsigned ow0 = cvt2bf(v0, v1), ow1 = cvt2bf(v2, v3);
  unsigned ow0e = 0, ow1e = 0;
  if (t < CHUNKS - 256) {            // c2 = 256+t -> b=15, fq2 = t+1
    int fq2 = t + 1;
    const float* hp2 = hx + (size_t)15 * HXS + n * UNITS;
    float e0, e1, e2, e3;
    if (fq2 < 16) {
      f32x2 a = *reinterpret_cast<const f32x2*>(hp2 + fq2 * 4 - 2);
      f32x2 d = *reinterpret_cast<const f32x2*>(hp2 + fq2 * 4);
      e0 = a[0]; e1 = a[1]; e2 = d[0]; e3 = d[1];
    } else {
      f32x2 a = *reinterpret_cast<const f32x2*>(hp2 + 62);
      e0 = a[0]; e1 = a[1]; e2 = 0.f; e3 = 0.f;
    }
    ow0e = cvt2bf(e0, e1); ow1e = cvt2bf(e2, e3);
    X8s[256 + t] = 0u;               // fq2 != 0
  }
  // X8s init (same t -> (b,fq) mapping): inputs bytes at fq==0, zero elsewhere
  X8s[t] = (fq0 == 0) ? pk4fp8(v0, v1, 0.f, 0.f) : 0u;

  int deg = cnt[n]; if (deg > CAP) deg = CAP;
  gather_write(X8, deg, epk + (size_t)n * CAP, t, ow0, ow1, ow0e, ow1e, Y, eds);

  int lane = t & 63, w = t >> 6, ml = lane & 15, s = lane >> 4;
  bf16x8 af[KTILES];
  build_afrag(Y, ml, s, af);

  const bf16x8* Wp = (const bf16x8*)W1p;
#pragma unroll
  for (int q = 0; q < 2; ++q) {
    int nt = w * 2 + q;
    f32x4 acc = {0.f, 0.f, 0.f, 0.f};
#pragma unroll
    for (int kt = 0; kt < KTILES; ++kt)
      acc = __builtin_amdgcn_mfma_f32_16x16x32_bf16(af[kt], Wp[(nt * KTILES + kt) * 64 + lane],
                                                    acc, 0, 0, 0);
    int o = nt * 16 + ml;           // output col; rows = batch s*4+r
    float bias = B1[o];
    int f = (o < UNITS ? o : o - UNITS) + IND, fqi = f >> 2, fr = f & 3;
    if (o < UNITS) {
#pragma unroll
      for (int r = 0; r < 4; ++r) {
        int b = s * 4 + r;
        float h = bf2f(Y[(b * LDSC + fqi) * 8 + fr]);   // h (bf16) from staged own-row x0 quad
        float sg = 1.f / (1.f + __expf(-(acc[r] + bias)));
        ((unsigned char*)X8s)[(b * FQ + fqi) * 4 + fr] = f2fp8(sg * h);
      }
    } else {
      int ou = o - UNITS;
#pragma unroll
      for (int r = 0; r < 4; ++r) {
        int b = s * 4 + r;
        float h = bf2f(Y[(b * LDSC + fqi) * 8 + fr]);
        float u = 1.f / (1.f + __expf(-(acc[r] + bias)));
        upk[(size_t)b * HXS + n * UNITS + ou] = cvt2bf(u, u * h);
      }
    }
  }
  __syncthreads();
  // coalesced fp8 row store
  X8c[(size_t)n * CHUNKS + t] = X8s[t];
  if (t < CHUNKS - 256) X8c[(size_t)n * CHUNKS + 256 + t] = X8s[256 + t];
}

// ------- candidate: gconv2 (MFMA) + tanh + GRU combine (out = uh + (1-u)*c) -------
__global__ __launch_bounds__(256) void cand_kernel(
    const unsigned* __restrict__ X8c, const short* __restrict__ W2p,
    const float* __restrict__ B2,
    const int* __restrict__ cnt, const u64* __restrict__ epk,
    const unsigned* __restrict__ upk, float* __restrict__ out) {
  __shared__ __align__(16) unsigned short Y[16 * LDSC * 8];
  __shared__ __align__(16) u64 eds[CAP];
  int n = blockIdx.x, t = threadIdx.x;

  // own row from fp8 table
  const unsigned* xrow = X8c + (size_t)n * CHUNKS;
  unsigned wo = xrow[t];
  f32x2 lo = __builtin_amdgcn_cvt_pk_f32_fp8((int)wo, false);
  f32x2 hi = __builtin_amdgcn_cvt_pk_f32_fp8((int)wo, true);
  unsigned ow0 = cvt2bf(lo[0], lo[1]), ow1 = cvt2bf(hi[0], hi[1]);
  unsigned ow0e = 0, ow1e = 0;
  if (t < CHUNKS - 256) {
    unsigned wo2 = xrow[256 + t];
    f32x2 lo2 = __builtin_amdgcn_cvt_pk_f32_fp8((int)wo2, false);
    f32x2 hi2 = __builtin_amdgcn_cvt_pk_f32_fp8((int)wo2, true);
    ow0e = cvt2bf(lo2[0], lo2[1]); ow1e = cvt2bf(hi2[0], hi2[1]);
  }

  int deg = cnt[n]; if (deg > CAP) deg = CAP;
  gather_write(X8c, deg, epk + (size_t)n * CAP, t, ow0, ow1, ow0e, ow1e, Y, eds);

  int lane = t & 63, w = t >> 6, ml = lane & 15, s = lane >> 4;
  bf16x8 af[KTILES];
  build_afrag(Y, ml, s, af);

  const bf16x8* Wp = (const bf16x8*)W2p;
  f32x4 acc = {0.f, 0.f, 0.f, 0.f};
#pragma unroll
  for (int kt = 0; kt < KTILES; ++kt)
    acc = __builtin_amdgcn_mfma_f32_16x16x32_bf16(af[kt], Wp[(w * KTILES + kt) * 64 + lane],
                                                  acc, 0, 0, 0);
  int o = w * 16 + ml;
  float bias = B2[o];
#pragma unroll
  for (int r = 0; r < 4; ++r) {
    int b = s * 4 + r;
    size_t idx = (size_t)b * HXS + n * UNITS + o;
    float x = acc[r] + bias;
    float c = 1.f - 2.f / (__expf(2.f * x) + 1.f);   // tanh
    unsigned pk = upk[idx];
    float u = bf2f((unsigned short)(pk & 0xffffu));
    float uh = bf2f((unsigned short)(pk >> 16));
    out[idx] = uh + (1.f - u) * c;
  }
}

extern "C" void kernel_launch(void* const* d_in, const int* in_sizes, int n_in,
                              void* d_out, int out_size, void* d_ws, size_t ws_size,
                              hipStream_t stream) {
  const float* inputs = (const float*)d_in[0];
  const float* hx     = (const float*)d_in[1];
  const float* eval   = (const float*)d_in[2];
  const float* w1mu   = (const float*)d_in[3];
  const float* w1ls   = (const float*)d_in[4];
  const float* b1mu   = (const float*)d_in[5];
  const float* b1ls   = (const float*)d_in[6];
  const float* w2mu   = (const float*)d_in[7];
  const float* w2ls   = (const float*)d_in[8];
  const float* b2mu   = (const float*)d_in[9];
  const float* b2ls   = (const float*)d_in[10];
  const float* ew1    = (const float*)d_in[11];
  const float* eb1    = (const float*)d_in[12];
  const float* ew2    = (const float*)d_in[13];
  const float* eb2    = (const float*)d_in[14];
  const int* erow     = (const int*)d_in[15];
  const int* ecol     = (const int*)d_in[16];
  float* out = (float*)d_out;

  char* p = (char*)d_ws;
  short* W1p = (short*)p;                   p += 20480 * 2;
  short* W2p = (short*)p;                   p += 10240 * 2;
  float* B1  = (float*)p;                   p += 128 * 4;
  float* B2  = (float*)p;                   p += 64 * 4;
  unsigned* X8  = (unsigned*)p;             p += (size_t)N_NODES * CHUNKS * 4;
  unsigned* X8c = (unsigned*)p;             p += (size_t)N_NODES * CHUNKS * 4;
  unsigned* upk = (unsigned*)p;             p += (size_t)BATCH * HXS * 4;
  int* cnt    = (int*)p;                    p += N_NODES * 4;
  u64* epk    = (u64*)p;                    p += (size_t)N_NODES * CAP * 8;

  hipMemsetAsync(cnt, 0, N_NODES * sizeof(int), stream);
  prep_kernel<<<16 + 313 + (N_NODES * CHUNKS) / 256, 256, 0, stream>>>(
      inputs, hx, w1mu, w1ls, ew1, b1mu, b1ls, eb1,
      w2mu, w2ls, ew2, b2mu, b2ls, eb2, erow, ecol, eval,
      W1p, W2p, B1, B2, cnt, epk, X8);
  gates_kernel<<<N_NODES, 256, 0, stream>>>(inputs, hx, X8, W1p, B1, cnt, epk, X8c, upk);
  cand_kernel<<<N_NODES, 256, 0, stream>>>(X8c, W2p, B2, cnt, epk, upk, out);
}